// Round 20
// baseline (175.052 us; speedup 1.0000x reference)
//
#include <hip/hip_runtime.h>
#include <hip/hip_bf16.h>
#include <stdint.h>
#include <math.h>

typedef short short8 __attribute__((ext_vector_type(8)));
typedef float f32x4 __attribute__((ext_vector_type(4)));
typedef unsigned short u16;

__device__ __forceinline__ u16 f2bf(float f) {
    unsigned u = __float_as_uint(f);
    unsigned r = 0x7FFFu + ((u >> 16) & 1u);
    return (u16)((u + r) >> 16);
}
__device__ __forceinline__ float bf2f(u16 h) {
    return __uint_as_float((unsigned)h << 16);
}

#define GL_LDS16(g, l)                                                         \
    __builtin_amdgcn_global_load_lds(                                          \
        (const __attribute__((address_space(1))) void*)(g),                    \
        (__attribute__((address_space(3))) void*)(l), 16, 0, 0)

// ------ merged prep: batch f32->bf16 convert + 4 weight transposes ----------
__global__ __launch_bounds__(256) void k_prep(
    const float* __restrict__ batch, u16* __restrict__ Ab, int nconv,
    const float* __restrict__ wq, const float* __restrict__ wk,
    const float* __restrict__ wv, const float* __restrict__ w0,
    u16* __restrict__ wcat, u16* __restrict__ w0T, int Dim) {
    __shared__ float tile[64][65];
    const int bid = blockIdx.x;
    const int t = threadIdx.x;
    if (bid < nconv) {
        int i = bid * 256 + t;
        const float4* s = (const float4*)batch + (size_t)i * 2;
        float4 a = s[0], b = s[1];
        uint4 o;
        o.x = (unsigned)f2bf(a.x) | ((unsigned)f2bf(a.y) << 16);
        o.y = (unsigned)f2bf(a.z) | ((unsigned)f2bf(a.w) << 16);
        o.z = (unsigned)f2bf(b.x) | ((unsigned)f2bf(b.y) << 16);
        o.w = (unsigned)f2bf(b.z) | ((unsigned)f2bf(b.w) << 16);
        ((uint4*)Ab)[i] = o;
        return;
    }
    const int id = bid - nconv;
    const int w = id >> 8, r = id & 255;
    const float* W = (w == 0) ? wq : (w == 1) ? wk : (w == 2) ? wv : w0;
    u16* WT = (w == 3) ? w0T : wcat + (size_t)w * Dim * Dim;
    const int k0 = (r & 15) * 64, n0 = (r >> 4) * 64;
    const int col = t & 63, rb = t >> 6;
#pragma unroll
    for (int i = 0; i < 16; ++i) {
        int rr = i * 4 + rb;
        tile[rr][col] = W[(size_t)(k0 + rr) * Dim + n0 + col];
    }
    __syncthreads();
#pragma unroll
    for (int i = 0; i < 16; ++i) {
        int rr = i * 4 + rb;
        WT[(size_t)(n0 + rr) * Dim + k0 + col] = f2bf(tile[col][rr]);
    }
}

// ------- FAT QKV GEMM: BM=256, BN=256, BK=64, 512 thr = 8 waves (2M x 4N) ---
// Per-wave output 128x64. acc[8][4] FORCED INTO AGPRs via "+a" asm touches
// (zero-cost if regalloc complies) -> VGPR live set ~100, no spill, while
// AGPRs hold the 128 accumulator regs (gfx950 MFMA reads/writes AGPR C/D).
// [R14/R15/R18: without this, compiler pinned 128 VGPR and spilled acc.]
// Ledger (3x correctness-verified): LDS 128 KiB, 2-tile dbuf of 6 units;
// stage t+1 during t: ph(kh,0): B(kh)'+A(0,kh)' ; ph(kh,1): A(1,kh)'.
// vmcnt(4) at mh0 phases; vmcnt(0) last tile. 2 barriers per K-tile.
// 16B-slot XOR swizzle (slot ^= (row>>1)&3) on global source + LDS read.
// Epilogue: LDS-staged coalesced stores, plane [256][256] u16 (=128 KiB).
__global__ __launch_bounds__(512) void k_gemmfat(
    const u16* __restrict__ A, const u16* __restrict__ BT,
    const float* __restrict__ b1, const float* __restrict__ b2,
    const float* __restrict__ b3,
    u16* __restrict__ Qh, u16* __restrict__ Ql,
    u16* __restrict__ Kh, u16* __restrict__ Kl,
    u16* __restrict__ Vb, int K, int ldo) {
    __shared__ __align__(16) u16 ldsbuf[65536];   // 128 KiB

    const int wg = blockIdx.x;
    const int xcd = wg & 7, idc = wg >> 3;          // grid 384 = 8 x 48
    const int ml = idc & 3, nbn = idc >> 2;         // 4 m-tiles per XCD chunk
    const int m0 = ((xcd << 2) + ml) << 8;          // *256
    const int n0 = nbn << 8;                        // *256
    const int tid = threadIdx.x;
    const int lane = tid & 63, wave = tid >> 6;
    const int wr = wave >> 2, wc = wave & 3;        // 2M x 4N
    const int r16 = lane & 15, kq = lane >> 4;
    const int nt = K >> 6;                          // 16 K-tiles

    int offA[2][4], offB[4];
#pragma unroll
    for (int mh = 0; mh < 2; ++mh)
#pragma unroll
        for (int mi = 0; mi < 4; ++mi) {
            int row = mh * 64 + mi * 16 + r16;
            offA[mh][mi] = row * 32 + ((kq ^ ((row >> 1) & 3)) << 3);
        }
#pragma unroll
    for (int n = 0; n < 4; ++n) {
        int row = wc * 64 + n * 16 + r16;
        offB[n] = row * 32 + ((kq ^ ((row >> 1) & 3)) << 3);
    }

    f32x4 acc[8][4];
#pragma unroll
    for (int m = 0; m < 8; ++m)
#pragma unroll
        for (int n = 0; n < 4; ++n) {
            acc[m][n] = (f32x4){0.f, 0.f, 0.f, 0.f};
            asm volatile("" : "+a"(acc[m][n]));   // pin accumulator to AGPRs
        }

    auto stageA = [&](int tn, int u, int kh) {     // 8 KB: 1 load/thread
        u16* base = ldsbuf + (tn & 1) * 16384 + kh * 8192 + u * 4096;
        int row = tid >> 2;
        int kk = ((tid & 3) ^ ((row >> 1) & 3)) << 3;
        GL_LDS16(A + (size_t)(m0 + u * 128 + row) * K + (tn << 6) + kh * 32 + kk,
                 base + ((tid & ~63) << 3));
    };
    auto stageB = [&](int tn, int kh) {            // 16 KB: 2 loads/thread
        u16* base = ldsbuf + 32768 + (tn & 1) * 16384 + kh * 8192;
#pragma unroll
        for (int r = 0; r < 2; ++r) {
            int li = (r << 9) + tid;
            int row = li >> 2;
            int kk = ((li & 3) ^ ((row >> 1) & 3)) << 3;
            GL_LDS16(BT + (size_t)(n0 + row) * K + (tn << 6) + kh * 32 + kk,
                     base + ((li & ~63) << 3));
        }
    };

    // prologue: tile 0 in ledger order (8 loads/thread)
    stageB(0, 0); stageA(0, 0, 0); stageA(0, 1, 0);
    stageB(0, 1); stageA(0, 0, 1); stageA(0, 1, 1);

    for (int tl = 0; tl < nt; ++tl) {
        const int buf = tl & 1;
#pragma unroll
        for (int kh = 0; kh < 2; ++kh) {
            if (kh == 0 || tl + 1 < nt)
                asm volatile("s_waitcnt vmcnt(4)" ::: "memory");
            else
                asm volatile("s_waitcnt vmcnt(0)" ::: "memory");
            __builtin_amdgcn_sched_barrier(0);
            __builtin_amdgcn_s_barrier();
            __builtin_amdgcn_sched_barrier(0);

            const u16* Abase = ldsbuf + buf * 16384 + kh * 8192 + wr * 4096;
            const u16* Bbase = ldsbuf + 32768 + buf * 16384 + kh * 8192;
            short8 a[4], bfr[4];
#pragma unroll
            for (int n = 0; n < 4; ++n)
                bfr[n] = *(const short8*)(Bbase + offB[n]);
#pragma unroll
            for (int mi = 0; mi < 4; ++mi)
                a[mi] = *(const short8*)(Abase + offA[0][mi]);
            if (tl + 1 < nt) { stageB(tl + 1, kh); stageA(tl + 1, 0, kh); }
            asm volatile("s_waitcnt lgkmcnt(0)" ::: "memory");
            __builtin_amdgcn_sched_barrier(0);
            __builtin_amdgcn_s_setprio(1);
#pragma unroll
            for (int mi = 0; mi < 4; ++mi)
#pragma unroll
                for (int n = 0; n < 4; ++n)
                    acc[mi][n] = __builtin_amdgcn_mfma_f32_16x16x32_bf16(
                        a[mi], bfr[n], acc[mi][n], 0, 0, 0);
            __builtin_amdgcn_s_setprio(0);
            __builtin_amdgcn_sched_barrier(0);

            // mh=1 phase: no barrier/vmcnt needed (data ready since mh0 wait)
#pragma unroll
            for (int mi = 0; mi < 4; ++mi)
                a[mi] = *(const short8*)(Abase + offA[1][mi]);
            if (tl + 1 < nt) stageA(tl + 1, 1, kh);
            asm volatile("s_waitcnt lgkmcnt(0)" ::: "memory");
            __builtin_amdgcn_sched_barrier(0);
            __builtin_amdgcn_s_setprio(1);
#pragma unroll
            for (int mi = 0; mi < 4; ++mi)
#pragma unroll
                for (int n = 0; n < 4; ++n)
                    acc[4 + mi][n] = __builtin_amdgcn_mfma_f32_16x16x32_bf16(
                        a[mi], bfr[n], acc[4 + mi][n], 0, 0, 0);
            __builtin_amdgcn_s_setprio(0);
            __builtin_amdgcn_sched_barrier(0);
        }
        // keep accumulators in AGPR class across the loop backedge
#pragma unroll
        for (int m = 0; m < 8; ++m)
#pragma unroll
            for (int n = 0; n < 4; ++n)
                asm volatile("" : "+a"(acc[m][n]));
    }

    // epilogue: seg split, LDS-staged coalesced stores
    const int seg = n0 >> 10;
    const float* bias = (seg == 0) ? b1 : (seg == 1) ? b2 : b3;
    u16* oh = (seg == 0) ? Qh : (seg == 1) ? Kh : Vb;
    u16* ol = (seg == 0) ? Ql : Kl;  // unused when seg==2
    const int nc0 = n0 & 1023;
    const int nplanes = (seg < 2) ? 2 : 1;
    for (int p = 0; p < nplanes; ++p) {
        __syncthreads();
#pragma unroll
        for (int n = 0; n < 4; ++n) {
            int col = wc * 64 + n * 16 + r16;
            float bvv = bias[nc0 + col];
#pragma unroll
            for (int mi = 0; mi < 8; ++mi) {
                int row = wr * 128 + mi * 16 + kq * 4;
#pragma unroll
                for (int j = 0; j < 4; ++j) {
                    float val = acc[mi][n][j] + bvv;
                    u16 hi = f2bf(val);
                    u16 w = p ? f2bf(val - bf2f(hi)) : hi;
                    ldsbuf[(row + j) * 256 + col] = w;
                }
            }
        }
        __syncthreads();
        u16* dst = p ? ol : oh;
#pragma unroll
        for (int i = 0; i < 16; ++i) {
            int li = (i << 9) + tid;            // 0..8191
            int row = li >> 5, ch = li & 31;
            short8 v = *(const short8*)&ldsbuf[row * 256 + ch * 8];
            *(short8*)(dst + (size_t)(m0 + row) * ldo + nc0 + ch * 8) = v;
        }
    }
}

// ---------------- thin GEMM (R13/R19-proven) for the output projection ------
__global__ __launch_bounds__(512) void k_gemmthin(
    const u16* __restrict__ A, const u16* __restrict__ BT,
    const float* __restrict__ b1, float* __restrict__ C,
    int K, int ldo) {
    __shared__ __align__(16) u16 ldsbuf[36864];   // 72 KiB

    const int wg = blockIdx.x;
    const int xcd = wg & 7, idc = wg >> 3;
    const int ml = idc & 3, nbn = idc >> 2;
    const int m0 = ((xcd << 2) + ml) << 8;
    const int n0 = nbn << 7;
    const int t = threadIdx.x;
    const int lane = t & 63, wave = t >> 6;
    const int wr = wave >> 1, wc = wave & 1;
    const int r16 = lane & 15, kq = lane >> 4;
    const int nt = K >> 6;
    const int np = nt << 1;

    int offA[4], offB[4];
#pragma unroll
    for (int mi = 0; mi < 4; ++mi) {
        int row = wr * 64 + mi * 16 + r16;
        offA[mi] = row * 32 + ((kq ^ ((row >> 1) & 3)) << 3);
    }
#pragma unroll
    for (int n = 0; n < 4; ++n) {
        int row = wc * 64 + n * 16 + r16;
        offB[n] = row * 32 + ((kq ^ ((row >> 1) & 3)) << 3);
    }

    f32x4 acc[4][4];
#pragma unroll
    for (int m = 0; m < 4; ++m)
#pragma unroll
        for (int n = 0; n < 4; ++n) acc[m][n] = (f32x4){0.f, 0.f, 0.f, 0.f};

    auto stage = [&](int h) {
        const int buf = h % 3;
        const int kt = ((h >> 1) << 6) + ((h & 1) << 5);
        u16* Abase = ldsbuf + buf * 12288;
        u16* Bbase = ldsbuf + buf * 12288 + 8192;
#pragma unroll
        for (int r = 0; r < 2; ++r) {
            int li = (r << 9) + t;
            int row = li >> 2;
            int kk = ((li & 3) ^ ((row >> 1) & 3)) << 3;
            GL_LDS16(A + (size_t)(m0 + row) * K + kt + kk,
                     Abase + ((li & ~63) << 3));
        }
        {
            int li = t;
            int row = li >> 2;
            int kk = ((li & 3) ^ ((row >> 1) & 3)) << 3;
            GL_LDS16(BT + (size_t)(n0 + row) * K + kt + kk,
                     Bbase + ((li & ~63) << 3));
        }
    };

    stage(0);
    stage(1);

    for (int p = 0; p < np; ++p) {
        if (p + 1 < np)
            asm volatile("s_waitcnt vmcnt(3)" ::: "memory");
        else
            asm volatile("s_waitcnt vmcnt(0)" ::: "memory");
        __builtin_amdgcn_sched_barrier(0);
        __builtin_amdgcn_s_barrier();
        __builtin_amdgcn_sched_barrier(0);

        const u16* base = ldsbuf + (p % 3) * 12288;
        short8 a[4], bfr[4];
#pragma unroll
        for (int mi = 0; mi < 4; ++mi)
            a[mi] = *(const short8*)(base + offA[mi]);
#pragma unroll
        for (int n = 0; n < 4; ++n)
            bfr[n] = *(const short8*)(base + 8192 + offB[n]);

        if (p + 2 < np) stage(p + 2);

        asm volatile("s_waitcnt lgkmcnt(0)" ::: "memory");
        __builtin_amdgcn_sched_barrier(0);
        __builtin_amdgcn_s_setprio(1);
#pragma unroll
        for (int mi = 0; mi < 4; ++mi)
#pragma unroll
            for (int n = 0; n < 4; ++n)
                acc[mi][n] = __builtin_amdgcn_mfma_f32_16x16x32_bf16(
                    a[mi], bfr[n], acc[mi][n], 0, 0, 0);
        __builtin_amdgcn_s_setprio(0);
        __builtin_amdgcn_sched_barrier(0);
    }

#pragma unroll
    for (int n = 0; n < 4; ++n) {
        int col = n0 + wc * 64 + n * 16 + r16;
        float bvv = b1[col];
#pragma unroll
        for (int mi = 0; mi < 4; ++mi) {
            int row = m0 + wr * 64 + mi * 16 + kq * 4;
#pragma unroll
            for (int j = 0; j < 4; ++j)
                C[(size_t)(row + j) * ldo + col] = acc[mi][n][j] + bvv;
        }
    }
}

// ---------------- MFMA diagonal-softmax + weighted = d*V --------------------
// 1024 blocks, 256 threads = 4 waves; (256,4): 4 blocks/CU = 1 round (R19).
__global__ __launch_bounds__(256, 4) void k_scores(
    const u16* __restrict__ Qhi, const u16* __restrict__ Qlo,
    const u16* __restrict__ Khi, const u16* __restrict__ Klo,
    const u16* __restrict__ Vb, const int* __restrict__ lengths,
    u16* __restrict__ Wt, int S, int D) {
    __shared__ __align__(16) u16 KsHi[2][4096];
    __shared__ __align__(16) u16 KsLo[2][4096];
    __shared__ float dbuf[128];

    const int wg = blockIdx.x;
    const int xcd = wg & 7, idc = wg >> 3;
    const int bh = (xcd << 4) + (idc >> 3);    // 16 (b,h) per XCD
    const int bx = idc & 7;
    const int b = bh >> 4, h = bh & 15;
    const int nchunk = S >> 6;                 // 16
    const int a0 = bx << 6;
    const int b0 = (nchunk - 1 - bx) << 6;

    const int t = threadIdx.x;
    const int lane = t & 63, wave = t >> 6;
    const int r16 = lane & 15, h2 = lane >> 4;
    const int len = lengths[b];

    short8 qh[2][2], ql[2][2];
#pragma unroll
    for (int m = 0; m < 2; ++m) {
        const int qm = m ? b0 : a0;
        const int row = qm + (wave << 4) + r16;
#pragma unroll
        for (int ks = 0; ks < 2; ++ks) {
            size_t off = ((size_t)(b * S) + row) * D + (h << 6) + (ks << 5) + (h2 << 3);
            qh[m][ks] = *(const short8*)(Qhi + off);
            ql[m][ks] = *(const short8*)(Qlo + off);
        }
    }

    float sum[2][4];
    float diag[2] = {-1e30f, -1e30f};
#pragma unroll
    for (int m = 0; m < 2; ++m)
#pragma unroll
        for (int r = 0; r < 4; ++r) sum[m][r] = 0.f;

    auto stage_k = [&](int j0, int bufi) {
#pragma unroll
        for (int p = 0; p < 2; ++p) {
            const int base_row = p * 32 + wave * 8;       // wave-uniform
            const int row = base_row + (lane >> 3);
            const int lc = (lane & 7) ^ (row & 7);
            size_t g = ((size_t)(b * S) + j0 + row) * D + (h << 6) + (lc << 3);
            GL_LDS16(Khi + g, &KsHi[bufi][base_row * 64]);
            GL_LDS16(Klo + g, &KsLo[bufi][base_row * 64]);
        }
    };

    const int jmax = min(b0 + 63, len - 1);
    stage_k(0, 0);
    for (int j0 = 0; j0 <= jmax; j0 += 64) {
        const int tb = (j0 >> 6) & 1;
        asm volatile("s_waitcnt vmcnt(0)" ::: "memory");
        __builtin_amdgcn_sched_barrier(0);
        __builtin_amdgcn_s_barrier();
        __builtin_amdgcn_sched_barrier(0);
        if (j0 + 64 <= jmax) stage_k(j0 + 64, tb ^ 1);

        f32x4 acc[2][4];
#pragma unroll
        for (int m = 0; m < 2; ++m)
#pragma unroll
            for (int n = 0; n < 4; ++n) acc[m][n] = (f32x4){0.f, 0.f, 0.f, 0.f};

#pragma unroll
        for (int ks = 0; ks < 2; ++ks) {
            short8 kh[4], kl[4];
#pragma unroll
            for (int n = 0; n < 4; ++n) {
                int row = (n << 4) + r16;
                int lc = (ks << 2) + h2;
                int phys = (row << 7) + ((lc ^ (row & 7)) << 4);
                kh[n] = *(const short8*)((const char*)&KsHi[tb][0] + phys);
                kl[n] = *(const short8*)((const char*)&KsLo[tb][0] + phys);
            }
#pragma unroll
            for (int m = 0; m < 2; ++m) {
                const int qm = m ? b0 : a0;
                if (j0 > qm) continue;
#pragma unroll
                for (int n = 0; n < 4; ++n) {
                    if (j0 + (n << 4) > qm + (wave << 4) + 15) continue;
                    acc[m][n] = __builtin_amdgcn_mfma_f32_16x16x32_bf16(qh[m][ks], kh[n], acc[m][n], 0, 0, 0);
                    acc[m][n] = __builtin_amdgcn_mfma_f32_16x16x32_bf16(qh[m][ks], kl[n], acc[m][n], 0, 0, 0);
                    acc[m][n] = __builtin_amdgcn_mfma_f32_16x16x32_bf16(ql[m][ks], kh[n], acc[m][n], 0, 0, 0);
                }
            }
        }

        const bool pad = (j0 + 64 > len);
#pragma unroll
        for (int m = 0; m < 2; ++m) {
            const int qm = m ? b0 : a0;
            if (j0 > qm) continue;
            const bool causal = (j0 == qm);
            if (causal || pad) {
#pragma unroll
                for (int n = 0; n < 4; ++n)
#pragma unroll
                    for (int r = 0; r < 4; ++r) {
                        int j = j0 + (n << 4) + r16;
                        int s = qm + (wave << 4) + (h2 << 2) + r;
                        if (j > s || j >= len) acc[m][n][r] = -1e30f;
                    }
                if (causal) {
#pragma unroll
                    for (int r = 0; r < 4; ++r)
                        if (r16 == (h2 << 2) + r) {
#pragma unroll
                            for (int n = 0; n < 4; ++n)
                                if (n == wave) diag[m] = acc[m][n][r];
                        }
                }
            }
#pragma unroll
            for (int r = 0; r < 4; ++r)
                sum[m][r] += __expf(acc[m][0][r]) + __expf(acc[m][1][r]) +
                             __expf(acc[m][2][r]) + __expf(acc[m][3][r]);
        }
    }

#pragma unroll
    for (int m = 0; m < 2; ++m)
#pragma unroll
        for (int r = 0; r < 4; ++r) {
            float sv = sum[m][r];
            sv += __shfl_xor(sv, 1);
            sv += __shfl_xor(sv, 2);
            sv += __shfl_xor(sv, 4);
            sv += __shfl_xor(sv, 8);
            sum[m][r] = sv;
        }

#pragma unroll
    for (int m = 0; m < 2; ++m)
#pragma unroll
        for (int r = 0; r < 4; ++r)
            if (r16 == (h2 << 2) + r)
                dbuf[(m << 6) + (wave << 4) + r16] = __expf(diag[m]) / sum[m][r];
    __syncthreads();

#pragma unroll
    for (int i = 0; i < 8; ++i) {
        int ri = i * 16 + (t >> 4);
        int c4 = (t & 15) << 2;
        int srow = (ri < 64) ? a0 + ri : b0 + ri - 64;
        float dv = dbuf[ri];
        const uint2 vv = *(const uint2*)(Vb + ((size_t)(b * S) + srow) * D + (h << 6) + c4);
        float x0 = bf2f((u16)(vv.x & 0xffffu)), x1 = bf2f((u16)(vv.x >> 16));
        float x2 = bf2f((u16)(vv.y & 0xffffu)), x3 = bf2f((u16)(vv.y >> 16));
        uint2 o;
        o.x = (unsigned)f2bf(x0 * dv) | ((unsigned)f2bf(x1 * dv) << 16);
        o.y = (unsigned)f2bf(x2 * dv) | ((unsigned)f2bf(x3 * dv) << 16);
        *(uint2*)(Wt + ((size_t)(b * S) + srow) * D + (h << 6) + c4) = o;
    }
}

extern "C" void kernel_launch(void* const* d_in, const int* in_sizes, int n_in,
                              void* d_out, int out_size, void* d_ws, size_t ws_size,
                              hipStream_t stream) {
    const float* batch = (const float*)d_in[0];
    const int* lengths = (const int*)d_in[1];
    const float* wq = (const float*)d_in[2];
    const float* bq = (const float*)d_in[3];
    const float* wk = (const float*)d_in[4];
    const float* bk = (const float*)d_in[5];
    const float* wv = (const float*)d_in[6];
    const float* bv = (const float*)d_in[7];
    const float* w0 = (const float*)d_in[8];
    const float* b0 = (const float*)d_in[9];

    const int D = in_sizes[3];            // 1024
    const int B = in_sizes[1];            // 8
    const int S = in_sizes[0] / (B * D);  // 1024
    const int H = 16;
    const int M = B * S;                  // 8192

    char* ws = (char*)d_ws;
    u16* Ab = (u16*)ws;    ws += (size_t)M * D * 2;
    u16* wcat = (u16*)ws;  ws += (size_t)3 * D * D * 2;   // [wqT; wkT; wvT]
    u16* w0T = (u16*)ws;   ws += (size_t)D * D * 2;
    u16* Qhi = (u16*)ws;   ws += (size_t)M * D * 2;
    u16* Qlo = (u16*)ws;   ws += (size_t)M * D * 2;
    u16* Khi = (u16*)ws;   ws += (size_t)M * D * 2;
    u16* Klo = (u16*)ws;   ws += (size_t)M * D * 2;
    u16* Vb = (u16*)ws;    ws += (size_t)M * D * 2;
    u16* Wtb = (u16*)ws;   ws += (size_t)M * D * 2;

    // 1. merged prep
    const int nconv = M * D / 8 / 256;    // 4096
    k_prep<<<nconv + 4 * (D / 64) * (D / 64), 256, 0, stream>>>(
        batch, Ab, nconv, wq, wk, wv, w0, wcat, w0T, D);

    // 2. fused QKV projection (fat 256x256, AGPR acc): 32 x 12 = 384 wgs
    k_gemmfat<<<(M / 256) * (3 * D / 256), 512, 0, stream>>>(
        Ab, wcat, bq, bk, bv, Qhi, Qlo, Khi, Klo, Vb, D, D);

    // 3. MFMA diagonal softmax + weighted = d*V (1024 blocks, 4/CU, 1 round)
    k_scores<<<(S / 128) * H * B, 256, 0, stream>>>(Qhi, Qlo, Khi, Klo, Vb,
                                                    lengths, Wtb, S, D);

    // 4. output projection -> d_out (f32): thin 256x128, 256 wgs
    k_gemmthin<<<(M / 256) * (D / 128), 512, 0, stream>>>(
        Wtb, w0T, b0, (float*)d_out, D, D);
}

// Round 21
// 149.342 us; speedup vs baseline: 1.1722x; 1.1722x over previous
//
#include <hip/hip_runtime.h>
#include <hip/hip_bf16.h>
#include <stdint.h>
#include <math.h>

typedef short short8 __attribute__((ext_vector_type(8)));
typedef float f32x4 __attribute__((ext_vector_type(4)));
typedef unsigned short u16;

__device__ __forceinline__ u16 f2bf(float f) {
    unsigned u = __float_as_uint(f);
    unsigned r = 0x7FFFu + ((u >> 16) & 1u);
    return (u16)((u + r) >> 16);
}
__device__ __forceinline__ float bf2f(u16 h) {
    return __uint_as_float((unsigned)h << 16);
}

#define GL_LDS16(g, l)                                                         \
    __builtin_amdgcn_global_load_lds(                                          \
        (const __attribute__((address_space(1))) void*)(g),                    \
        (__attribute__((address_space(3))) void*)(l), 16, 0, 0)

// ------ merged prep: batch f32->bf16 convert + 4 weight transposes ----------
__global__ __launch_bounds__(256) void k_prep(
    const float* __restrict__ batch, u16* __restrict__ Ab, int nconv,
    const float* __restrict__ wq, const float* __restrict__ wk,
    const float* __restrict__ wv, const float* __restrict__ w0,
    u16* __restrict__ wcat, u16* __restrict__ w0T, int Dim) {
    __shared__ float tile[64][65];
    const int bid = blockIdx.x;
    const int t = threadIdx.x;
    if (bid < nconv) {
        int i = bid * 256 + t;
        const float4* s = (const float4*)batch + (size_t)i * 2;
        float4 a = s[0], b = s[1];
        uint4 o;
        o.x = (unsigned)f2bf(a.x) | ((unsigned)f2bf(a.y) << 16);
        o.y = (unsigned)f2bf(a.z) | ((unsigned)f2bf(a.w) << 16);
        o.z = (unsigned)f2bf(b.x) | ((unsigned)f2bf(b.y) << 16);
        o.w = (unsigned)f2bf(b.z) | ((unsigned)f2bf(b.w) << 16);
        ((uint4*)Ab)[i] = o;
        return;
    }
    const int id = bid - nconv;
    const int w = id >> 8, r = id & 255;
    const float* W = (w == 0) ? wq : (w == 1) ? wk : (w == 2) ? wv : w0;
    u16* WT = (w == 3) ? w0T : wcat + (size_t)w * Dim * Dim;
    const int k0 = (r & 15) * 64, n0 = (r >> 4) * 64;
    const int col = t & 63, rb = t >> 6;
#pragma unroll
    for (int i = 0; i < 16; ++i) {
        int rr = i * 4 + rb;
        tile[rr][col] = W[(size_t)(k0 + rr) * Dim + n0 + col];
    }
    __syncthreads();
#pragma unroll
    for (int i = 0; i < 16; ++i) {
        int rr = i * 4 + rb;
        WT[(size_t)(n0 + rr) * Dim + k0 + col] = f2bf(tile[col][rr]);
    }
}

// ---------------- phase-pipelined bf16 MFMA GEMM: BM=256, BN=128, BK=64 -----
// [R13/R19-proven: VGPR 84, no spill, QKV ~73us. Fat-tile postmortem
//  R10/R12/R14/R15/R18/R20: every 256x256 attempt (launch_bounds,
//  waves_per_eu, "+a" AGPR pinning) compiled to a hard 128-VGPR cap and
//  spilled acc (+45MB scratch) -> ~107us. Fat tile unreachable via hipcc.]
// LDS 72 KiB: 3-buffer HALF-TILE rotation, buf = phase % 3, each buf =
// A-half [256x32] (16K) + B-half [128x32] (8K). Phase p: vmcnt(3) -> raw
// s_barrier -> 12 ds_read_b128 -> stage(p+2) into buf (p-1)%3 (WAR-safe)
// -> lgkmcnt(0) -> 16 MFMA (setprio 1). vmcnt(0) only at last phase.
// 16B-slot XOR swizzle (slot ^= (row>>1)&3) on global source + LDS read.
// FUSED=1 epilogue: LDS-staged coalesced stores (plane [256][128] u16).
template <int FUSED>
__global__ __launch_bounds__(512) void k_gemm8(
    const u16* __restrict__ A, const u16* __restrict__ BT,
    const float* __restrict__ b1, const float* __restrict__ b2,
    const float* __restrict__ b3,
    u16* __restrict__ Qh, u16* __restrict__ Ql,
    u16* __restrict__ Kh, u16* __restrict__ Kl,
    u16* __restrict__ Vb, float* __restrict__ C,
    int K, int ldo) {
    __shared__ __align__(16) u16 ldsbuf[36864];   // 72 KiB

    const int wg = blockIdx.x;
    const int xcd = wg & 7, idc = wg >> 3;          // grid % 8 == 0
    const int ml = idc & 3, nbn = idc >> 2;         // 4 m-tiles per XCD chunk
    const int m0 = ((xcd << 2) + ml) << 8;          // *256
    const int n0 = nbn << 7;                        // *128
    const int t = threadIdx.x;
    const int lane = t & 63, wave = t >> 6;
    const int wr = wave >> 1, wc = wave & 1;
    const int r16 = lane & 15, kq = lane >> 4;
    const int nt = K >> 6;                          // K-tiles (16)
    const int np = nt << 1;                         // phases (32)

    int offA[4], offB[4];
#pragma unroll
    for (int mi = 0; mi < 4; ++mi) {
        int row = wr * 64 + mi * 16 + r16;
        offA[mi] = row * 32 + ((kq ^ ((row >> 1) & 3)) << 3);
    }
#pragma unroll
    for (int n = 0; n < 4; ++n) {
        int row = wc * 64 + n * 16 + r16;
        offB[n] = row * 32 + ((kq ^ ((row >> 1) & 3)) << 3);
    }

    f32x4 acc[4][4];
#pragma unroll
    for (int m = 0; m < 4; ++m)
#pragma unroll
        for (int n = 0; n < 4; ++n) acc[m][n] = (f32x4){0.f, 0.f, 0.f, 0.f};

    auto stage = [&](int h) {
        const int buf = h % 3;
        const int kt = ((h >> 1) << 6) + ((h & 1) << 5);
        u16* Abase = ldsbuf + buf * 12288;
        u16* Bbase = ldsbuf + buf * 12288 + 8192;
#pragma unroll
        for (int r = 0; r < 2; ++r) {
            int li = (r << 9) + t;
            int row = li >> 2;
            int kk = ((li & 3) ^ ((row >> 1) & 3)) << 3;
            GL_LDS16(A + (size_t)(m0 + row) * K + kt + kk,
                     Abase + ((li & ~63) << 3));
        }
        {
            int li = t;
            int row = li >> 2;
            int kk = ((li & 3) ^ ((row >> 1) & 3)) << 3;
            GL_LDS16(BT + (size_t)(n0 + row) * K + kt + kk,
                     Bbase + ((li & ~63) << 3));
        }
    };

    stage(0);
    stage(1);

    for (int p = 0; p < np; ++p) {
        if (p + 1 < np)
            asm volatile("s_waitcnt vmcnt(3)" ::: "memory");
        else
            asm volatile("s_waitcnt vmcnt(0)" ::: "memory");
        __builtin_amdgcn_sched_barrier(0);
        __builtin_amdgcn_s_barrier();
        __builtin_amdgcn_sched_barrier(0);

        const u16* base = ldsbuf + (p % 3) * 12288;
        short8 a[4], bfr[4];
#pragma unroll
        for (int mi = 0; mi < 4; ++mi)
            a[mi] = *(const short8*)(base + offA[mi]);
#pragma unroll
        for (int n = 0; n < 4; ++n)
            bfr[n] = *(const short8*)(base + 8192 + offB[n]);

        if (p + 2 < np) stage(p + 2);

        asm volatile("s_waitcnt lgkmcnt(0)" ::: "memory");
        __builtin_amdgcn_sched_barrier(0);
        __builtin_amdgcn_s_setprio(1);
#pragma unroll
        for (int mi = 0; mi < 4; ++mi)
#pragma unroll
            for (int n = 0; n < 4; ++n)
                acc[mi][n] = __builtin_amdgcn_mfma_f32_16x16x32_bf16(
                    a[mi], bfr[n], acc[mi][n], 0, 0, 0);
        __builtin_amdgcn_s_setprio(0);
        __builtin_amdgcn_sched_barrier(0);
    }

    if (FUSED) {
        const int seg = n0 >> 10;
        const float* bias = (seg == 0) ? b1 : (seg == 1) ? b2 : b3;
        u16* oh = (seg == 0) ? Qh : (seg == 1) ? Kh : Vb;
        u16* ol = (seg == 0) ? Ql : Kl;  // unused when seg==2
        const int nc0 = n0 & 1023;
        const int nplanes = (seg < 2) ? 2 : 1;
        u16* lds = ldsbuf;               // retired pipeline LDS: [256][128] u16
        for (int p = 0; p < nplanes; ++p) {
            __syncthreads();             // pipeline LDS free / prev plane done
#pragma unroll
            for (int n = 0; n < 4; ++n) {
                int col = wc * 64 + n * 16 + r16;
                float bvv = bias[nc0 + col];
#pragma unroll
                for (int mi = 0; mi < 4; ++mi) {
                    int row = wr * 64 + mi * 16 + kq * 4;
#pragma unroll
                    for (int j = 0; j < 4; ++j) {
                        float val = acc[mi][n][j] + bvv;
                        u16 hi = f2bf(val);
                        u16 w = p ? f2bf(val - bf2f(hi)) : hi;
                        lds[(row + j) * 128 + col] = w;
                    }
                }
            }
            __syncthreads();
            u16* dst = p ? ol : oh;
#pragma unroll
            for (int i = 0; i < 8; ++i) {
                int li = (i << 9) + t;          // 0..4095
                int row = li >> 4, ch = li & 15;
                short8 v = *(const short8*)&lds[row * 128 + ch * 8];
                *(short8*)(dst + (size_t)(m0 + row) * ldo + nc0 + ch * 8) = v;
            }
        }
    } else {
#pragma unroll
        for (int n = 0; n < 4; ++n) {
            int col = n0 + wc * 64 + n * 16 + r16;
            float bvv = b1[col];
#pragma unroll
            for (int mi = 0; mi < 4; ++mi) {
                int row = m0 + wr * 64 + mi * 16 + kq * 4;
#pragma unroll
                for (int j = 0; j < 4; ++j)
                    C[(size_t)(row + j) * ldo + col] = acc[mi][n][j] + bvv;
            }
        }
    }
}

// ------- out-projection GEMM: BM=128, BN=128, BK=64 (full-machine grid) -----
// 512 threads = 8 waves (4M x 2N); per-wave output 32x64 (2m x 4n frags,
// acc 32 regs). Same R13 schedule, scaled: stage = 2 loads/thread (A-half
// [128x32] 8K + B-half [128x32] 8K), 3-buffer rotation (48 KiB), vmcnt(2)
// steady / vmcnt(0) last. Grid 512 wgs = 1 FULL round at 2 blocks/CU
// (R19's BM=256 out-GEMM: 256 wgs = half the CU slots idle).
__global__ __launch_bounds__(512) void k_gemmout(
    const u16* __restrict__ A, const u16* __restrict__ BT,
    const float* __restrict__ b1, float* __restrict__ C,
    int K, int ldo) {
    __shared__ __align__(16) u16 ldsbuf[24576];   // 48 KiB

    const int wg = blockIdx.x;
    const int xcd = wg & 7, idc = wg >> 3;          // 64 per XCD chunk
    const int ml = idc & 7, nbn = idc >> 3;         // 8 m-tiles per chunk
    const int m0 = ((xcd << 3) + ml) << 7;          // *128
    const int n0 = nbn << 7;                        // *128
    const int t = threadIdx.x;
    const int lane = t & 63, wave = t >> 6;
    const int wr = wave >> 1, wc = wave & 1;
    const int r16 = lane & 15, kq = lane >> 4;
    const int nt = K >> 6;
    const int np = nt << 1;

    int offA[2], offB[4];
#pragma unroll
    for (int mi = 0; mi < 2; ++mi) {
        int row = wr * 32 + mi * 16 + r16;
        offA[mi] = row * 32 + ((kq ^ ((row >> 1) & 3)) << 3);
    }
#pragma unroll
    for (int n = 0; n < 4; ++n) {
        int row = wc * 64 + n * 16 + r16;
        offB[n] = row * 32 + ((kq ^ ((row >> 1) & 3)) << 3);
    }

    f32x4 acc[2][4];
#pragma unroll
    for (int m = 0; m < 2; ++m)
#pragma unroll
        for (int n = 0; n < 4; ++n) acc[m][n] = (f32x4){0.f, 0.f, 0.f, 0.f};

    // stage half-tile h into buf h%3: A 8KB (1 load) + B 8KB (1 load)
    auto stage = [&](int h) {
        const int buf = h % 3;
        const int kt = ((h >> 1) << 6) + ((h & 1) << 5);
        u16* Abase = ldsbuf + buf * 8192;
        u16* Bbase = Abase + 4096;
        {
            int li = t;
            int row = li >> 2;
            int kk = ((li & 3) ^ ((row >> 1) & 3)) << 3;
            GL_LDS16(A + (size_t)(m0 + row) * K + kt + kk,
                     Abase + ((li & ~63) << 3));
        }
        {
            int li = t;
            int row = li >> 2;
            int kk = ((li & 3) ^ ((row >> 1) & 3)) << 3;
            GL_LDS16(BT + (size_t)(n0 + row) * K + kt + kk,
                     Bbase + ((li & ~63) << 3));
        }
    };

    stage(0);
    stage(1);

    for (int p = 0; p < np; ++p) {
        if (p + 1 < np)
            asm volatile("s_waitcnt vmcnt(2)" ::: "memory");
        else
            asm volatile("s_waitcnt vmcnt(0)" ::: "memory");
        __builtin_amdgcn_sched_barrier(0);
        __builtin_amdgcn_s_barrier();
        __builtin_amdgcn_sched_barrier(0);

        const u16* base = ldsbuf + (p % 3) * 8192;
        short8 a[2], bfr[4];
#pragma unroll
        for (int mi = 0; mi < 2; ++mi)
            a[mi] = *(const short8*)(base + offA[mi]);
#pragma unroll
        for (int n = 0; n < 4; ++n)
            bfr[n] = *(const short8*)(base + 4096 + offB[n]);

        if (p + 2 < np) stage(p + 2);

        asm volatile("s_waitcnt lgkmcnt(0)" ::: "memory");
        __builtin_amdgcn_sched_barrier(0);
        __builtin_amdgcn_s_setprio(1);
#pragma unroll
        for (int mi = 0; mi < 2; ++mi)
#pragma unroll
            for (int n = 0; n < 4; ++n)
                acc[mi][n] = __builtin_amdgcn_mfma_f32_16x16x32_bf16(
                    a[mi], bfr[n], acc[mi][n], 0, 0, 0);
        __builtin_amdgcn_s_setprio(0);
        __builtin_amdgcn_sched_barrier(0);
    }

#pragma unroll
    for (int n = 0; n < 4; ++n) {
        int col = n0 + wc * 64 + n * 16 + r16;
        float bvv = b1[col];
#pragma unroll
        for (int mi = 0; mi < 2; ++mi) {
            int row = m0 + wr * 32 + mi * 16 + kq * 4;
#pragma unroll
            for (int j = 0; j < 4; ++j)
                C[(size_t)(row + j) * ldo + col] = acc[mi][n][j] + bvv;
        }
    }
}

// ---------------- MFMA diagonal-softmax + weighted = d*V --------------------
// 1024 blocks, 256 threads = 4 waves; (256,4): 4 blocks/CU = 1 round (R19).
__global__ __launch_bounds__(256, 4) void k_scores(
    const u16* __restrict__ Qhi, const u16* __restrict__ Qlo,
    const u16* __restrict__ Khi, const u16* __restrict__ Klo,
    const u16* __restrict__ Vb, const int* __restrict__ lengths,
    u16* __restrict__ Wt, int S, int D) {
    __shared__ __align__(16) u16 KsHi[2][4096];
    __shared__ __align__(16) u16 KsLo[2][4096];
    __shared__ float dbuf[128];

    const int wg = blockIdx.x;
    const int xcd = wg & 7, idc = wg >> 3;
    const int bh = (xcd << 4) + (idc >> 3);    // 16 (b,h) per XCD
    const int bx = idc & 7;
    const int b = bh >> 4, h = bh & 15;
    const int nchunk = S >> 6;                 // 16
    const int a0 = bx << 6;
    const int b0 = (nchunk - 1 - bx) << 6;

    const int t = threadIdx.x;
    const int lane = t & 63, wave = t >> 6;
    const int r16 = lane & 15, h2 = lane >> 4;
    const int len = lengths[b];

    short8 qh[2][2], ql[2][2];
#pragma unroll
    for (int m = 0; m < 2; ++m) {
        const int qm = m ? b0 : a0;
        const int row = qm + (wave << 4) + r16;
#pragma unroll
        for (int ks = 0; ks < 2; ++ks) {
            size_t off = ((size_t)(b * S) + row) * D + (h << 6) + (ks << 5) + (h2 << 3);
            qh[m][ks] = *(const short8*)(Qhi + off);
            ql[m][ks] = *(const short8*)(Qlo + off);
        }
    }

    float sum[2][4];
    float diag[2] = {-1e30f, -1e30f};
#pragma unroll
    for (int m = 0; m < 2; ++m)
#pragma unroll
        for (int r = 0; r < 4; ++r) sum[m][r] = 0.f;

    auto stage_k = [&](int j0, int bufi) {
#pragma unroll
        for (int p = 0; p < 2; ++p) {
            const int base_row = p * 32 + wave * 8;       // wave-uniform
            const int row = base_row + (lane >> 3);
            const int lc = (lane & 7) ^ (row & 7);
            size_t g = ((size_t)(b * S) + j0 + row) * D + (h << 6) + (lc << 3);
            GL_LDS16(Khi + g, &KsHi[bufi][base_row * 64]);
            GL_LDS16(Klo + g, &KsLo[bufi][base_row * 64]);
        }
    };

    const int jmax = min(b0 + 63, len - 1);
    stage_k(0, 0);
    for (int j0 = 0; j0 <= jmax; j0 += 64) {
        const int tb = (j0 >> 6) & 1;
        asm volatile("s_waitcnt vmcnt(0)" ::: "memory");
        __builtin_amdgcn_sched_barrier(0);
        __builtin_amdgcn_s_barrier();
        __builtin_amdgcn_sched_barrier(0);
        if (j0 + 64 <= jmax) stage_k(j0 + 64, tb ^ 1);

        f32x4 acc[2][4];
#pragma unroll
        for (int m = 0; m < 2; ++m)
#pragma unroll
            for (int n = 0; n < 4; ++n) acc[m][n] = (f32x4){0.f, 0.f, 0.f, 0.f};

#pragma unroll
        for (int ks = 0; ks < 2; ++ks) {
            short8 kh[4], kl[4];
#pragma unroll
            for (int n = 0; n < 4; ++n) {
                int row = (n << 4) + r16;
                int lc = (ks << 2) + h2;
                int phys = (row << 7) + ((lc ^ (row & 7)) << 4);
                kh[n] = *(const short8*)((const char*)&KsHi[tb][0] + phys);
                kl[n] = *(const short8*)((const char*)&KsLo[tb][0] + phys);
            }
#pragma unroll
            for (int m = 0; m < 2; ++m) {
                const int qm = m ? b0 : a0;
                if (j0 > qm) continue;
#pragma unroll
                for (int n = 0; n < 4; ++n) {
                    if (j0 + (n << 4) > qm + (wave << 4) + 15) continue;
                    acc[m][n] = __builtin_amdgcn_mfma_f32_16x16x32_bf16(qh[m][ks], kh[n], acc[m][n], 0, 0, 0);
                    acc[m][n] = __builtin_amdgcn_mfma_f32_16x16x32_bf16(qh[m][ks], kl[n], acc[m][n], 0, 0, 0);
                    acc[m][n] = __builtin_amdgcn_mfma_f32_16x16x32_bf16(ql[m][ks], kh[n], acc[m][n], 0, 0, 0);
                }
            }
        }

        const bool pad = (j0 + 64 > len);
#pragma unroll
        for (int m = 0; m < 2; ++m) {
            const int qm = m ? b0 : a0;
            if (j0 > qm) continue;
            const bool causal = (j0 == qm);
            if (causal || pad) {
#pragma unroll
                for (int n = 0; n < 4; ++n)
#pragma unroll
                    for (int r = 0; r < 4; ++r) {
                        int j = j0 + (n << 4) + r16;
                        int s = qm + (wave << 4) + (h2 << 2) + r;
                        if (j > s || j >= len) acc[m][n][r] = -1e30f;
                    }
                if (causal) {
#pragma unroll
                    for (int r = 0; r < 4; ++r)
                        if (r16 == (h2 << 2) + r) {
#pragma unroll
                            for (int n = 0; n < 4; ++n)
                                if (n == wave) diag[m] = acc[m][n][r];
                        }
                }
            }
#pragma unroll
            for (int r = 0; r < 4; ++r)
                sum[m][r] += __expf(acc[m][0][r]) + __expf(acc[m][1][r]) +
                             __expf(acc[m][2][r]) + __expf(acc[m][3][r]);
        }
    }

#pragma unroll
    for (int m = 0; m < 2; ++m)
#pragma unroll
        for (int r = 0; r < 4; ++r) {
            float sv = sum[m][r];
            sv += __shfl_xor(sv, 1);
            sv += __shfl_xor(sv, 2);
            sv += __shfl_xor(sv, 4);
            sv += __shfl_xor(sv, 8);
            sum[m][r] = sv;
        }

#pragma unroll
    for (int m = 0; m < 2; ++m)
#pragma unroll
        for (int r = 0; r < 4; ++r)
            if (r16 == (h2 << 2) + r)
                dbuf[(m << 6) + (wave << 4) + r16] = __expf(diag[m]) / sum[m][r];
    __syncthreads();

#pragma unroll
    for (int i = 0; i < 8; ++i) {
        int ri = i * 16 + (t >> 4);
        int c4 = (t & 15) << 2;
        int srow = (ri < 64) ? a0 + ri : b0 + ri - 64;
        float dv = dbuf[ri];
        const uint2 vv = *(const uint2*)(Vb + ((size_t)(b * S) + srow) * D + (h << 6) + c4);
        float x0 = bf2f((u16)(vv.x & 0xffffu)), x1 = bf2f((u16)(vv.x >> 16));
        float x2 = bf2f((u16)(vv.y & 0xffffu)), x3 = bf2f((u16)(vv.y >> 16));
        uint2 o;
        o.x = (unsigned)f2bf(x0 * dv) | ((unsigned)f2bf(x1 * dv) << 16);
        o.y = (unsigned)f2bf(x2 * dv) | ((unsigned)f2bf(x3 * dv) << 16);
        *(uint2*)(Wt + ((size_t)(b * S) + srow) * D + (h << 6) + c4) = o;
    }
}

extern "C" void kernel_launch(void* const* d_in, const int* in_sizes, int n_in,
                              void* d_out, int out_size, void* d_ws, size_t ws_size,
                              hipStream_t stream) {
    const float* batch = (const float*)d_in[0];
    const int* lengths = (const int*)d_in[1];
    const float* wq = (const float*)d_in[2];
    const float* bq = (const float*)d_in[3];
    const float* wk = (const float*)d_in[4];
    const float* bk = (const float*)d_in[5];
    const float* wv = (const float*)d_in[6];
    const float* bv = (const float*)d_in[7];
    const float* w0 = (const float*)d_in[8];
    const float* b0 = (const float*)d_in[9];

    const int D = in_sizes[3];            // 1024
    const int B = in_sizes[1];            // 8
    const int S = in_sizes[0] / (B * D);  // 1024
    const int H = 16;
    const int M = B * S;                  // 8192

    char* ws = (char*)d_ws;
    u16* Ab = (u16*)ws;    ws += (size_t)M * D * 2;
    u16* wcat = (u16*)ws;  ws += (size_t)3 * D * D * 2;   // [wqT; wkT; wvT]
    u16* w0T = (u16*)ws;   ws += (size_t)D * D * 2;
    u16* Qhi = (u16*)ws;   ws += (size_t)M * D * 2;
    u16* Qlo = (u16*)ws;   ws += (size_t)M * D * 2;
    u16* Khi = (u16*)ws;   ws += (size_t)M * D * 2;
    u16* Klo = (u16*)ws;   ws += (size_t)M * D * 2;
    u16* Vb = (u16*)ws;    ws += (size_t)M * D * 2;
    u16* Wtb = (u16*)ws;   ws += (size_t)M * D * 2;

    // 1. merged prep: convert (4096 blocks) + 4 transposes (1024 blocks)
    const int nconv = M * D / 8 / 256;    // 4096
    k_prep<<<nconv + 4 * (D / 64) * (D / 64), 256, 0, stream>>>(
        batch, Ab, nconv, wq, wk, wv, w0, wcat, w0T, D);

    // 2. fused QKV projection: (8192/256) x (3072/128) = 768 wgs
    k_gemm8<1><<<(M / 256) * (3 * D / 128), 512, 0, stream>>>(
        Ab, wcat, bq, bk, bv, Qhi, Qlo, Khi, Klo, Vb, nullptr, D, D);

    // 3. MFMA diagonal softmax + weighted = d*V (1024 blocks, 4/CU, 1 round)
    k_scores<<<(S / 128) * H * B, 256, 0, stream>>>(Qhi, Qlo, Khi, Klo, Vb,
                                                    lengths, Wtb, S, D);

    // 4. output projection -> d_out (f32): BM=128 grid 512 wgs = full machine
    k_gemmout<<<(M / 128) * (D / 128), 512, 0, stream>>>(
        Wtb, w0T, b0, (float*)d_out, D, D);
}

// Round 22
// 148.217 us; speedup vs baseline: 1.1811x; 1.0076x over previous
//
#include <hip/hip_runtime.h>
#include <hip/hip_bf16.h>
#include <stdint.h>
#include <math.h>

typedef short short8 __attribute__((ext_vector_type(8)));
typedef float f32x4 __attribute__((ext_vector_type(4)));
typedef unsigned short u16;

__device__ __forceinline__ u16 f2bf(float f) {
    unsigned u = __float_as_uint(f);
    unsigned r = 0x7FFFu + ((u >> 16) & 1u);
    return (u16)((u + r) >> 16);
}
__device__ __forceinline__ float bf2f(u16 h) {
    return __uint_as_float((unsigned)h << 16);
}

#define GL_LDS16(g, l)                                                         \
    __builtin_amdgcn_global_load_lds(                                          \
        (const __attribute__((address_space(1))) void*)(g),                    \
        (__attribute__((address_space(3))) void*)(l), 16, 0, 0)

// ------ merged prep: batch f32->bf16 convert + 4 weight transposes ----------
__global__ __launch_bounds__(256) void k_prep(
    const float* __restrict__ batch, u16* __restrict__ Ab, int nconv,
    const float* __restrict__ wq, const float* __restrict__ wk,
    const float* __restrict__ wv, const float* __restrict__ w0,
    u16* __restrict__ wcat, u16* __restrict__ w0T, int Dim) {
    __shared__ float tile[64][65];
    const int bid = blockIdx.x;
    const int t = threadIdx.x;
    if (bid < nconv) {
        int i = bid * 256 + t;
        const float4* s = (const float4*)batch + (size_t)i * 2;
        float4 a = s[0], b = s[1];
        uint4 o;
        o.x = (unsigned)f2bf(a.x) | ((unsigned)f2bf(a.y) << 16);
        o.y = (unsigned)f2bf(a.z) | ((unsigned)f2bf(a.w) << 16);
        o.z = (unsigned)f2bf(b.x) | ((unsigned)f2bf(b.y) << 16);
        o.w = (unsigned)f2bf(b.z) | ((unsigned)f2bf(b.w) << 16);
        ((uint4*)Ab)[i] = o;
        return;
    }
    const int id = bid - nconv;
    const int w = id >> 8, r = id & 255;
    const float* W = (w == 0) ? wq : (w == 1) ? wk : (w == 2) ? wv : w0;
    u16* WT = (w == 3) ? w0T : wcat + (size_t)w * Dim * Dim;
    const int k0 = (r & 15) * 64, n0 = (r >> 4) * 64;
    const int col = t & 63, rb = t >> 6;
#pragma unroll
    for (int i = 0; i < 16; ++i) {
        int rr = i * 4 + rb;
        tile[rr][col] = W[(size_t)(k0 + rr) * Dim + n0 + col];
    }
    __syncthreads();
#pragma unroll
    for (int i = 0; i < 16; ++i) {
        int rr = i * 4 + rb;
        WT[(size_t)(n0 + rr) * Dim + k0 + col] = f2bf(tile[col][rr]);
    }
}

// ---------------- phase-pipelined bf16 MFMA GEMM: BM=256, BN=128, BK=64 -----
// 512 threads = 8 waves (4M x 2N); per-wave output 64x64 (4m x 4n frags).
// [R13/R19-proven optimum: VGPR 84, no spill, QKV ~73us = the thin-tile
//  LDS ceiling x 62% schedule efficiency. Fat-tile postmortem (6 attempts:
//  plain/launch_bounds x2/waves_per_eu/"+a" AGPR pin): hipcc always pins
//  128 VGPR and spills acc -> +45MB scratch -> ~107us. Compiler-bound.]
// LDS 72 KiB: 3-buffer HALF-TILE rotation, buf = phase % 3, each buf =
// A-half [256x32] (16K) + B-half [128x32] (8K). Phase p: vmcnt(3) -> raw
// s_barrier -> 12 ds_read_b128 -> stage(p+2) into buf (p-1)%3 (WAR-safe)
// -> lgkmcnt(0) -> 16 MFMA (setprio 1). vmcnt(0) only at last phase.
// 16B-slot XOR swizzle (slot ^= (row>>1)&3) on global source + LDS read.
// FUSED=1 epilogue: LDS-staged coalesced stores (plane [256][128] u16).
template <int FUSED>
__global__ __launch_bounds__(512) void k_gemm8(
    const u16* __restrict__ A, const u16* __restrict__ BT,
    const float* __restrict__ b1, const float* __restrict__ b2,
    const float* __restrict__ b3,
    u16* __restrict__ Qh, u16* __restrict__ Ql,
    u16* __restrict__ Kh, u16* __restrict__ Kl,
    u16* __restrict__ Vb, float* __restrict__ C,
    int K, int ldo) {
    __shared__ __align__(16) u16 ldsbuf[36864];   // 72 KiB

    const int wg = blockIdx.x;
    const int xcd = wg & 7, idc = wg >> 3;          // grid % 8 == 0
    const int ml = idc & 3, nbn = idc >> 2;         // 4 m-tiles per XCD chunk
    const int m0 = ((xcd << 2) + ml) << 8;          // *256
    const int n0 = nbn << 7;                        // *128
    const int t = threadIdx.x;
    const int lane = t & 63, wave = t >> 6;
    const int wr = wave >> 1, wc = wave & 1;
    const int r16 = lane & 15, kq = lane >> 4;
    const int nt = K >> 6;                          // K-tiles (16)
    const int np = nt << 1;                         // phases (32)

    int offA[4], offB[4];
#pragma unroll
    for (int mi = 0; mi < 4; ++mi) {
        int row = wr * 64 + mi * 16 + r16;
        offA[mi] = row * 32 + ((kq ^ ((row >> 1) & 3)) << 3);
    }
#pragma unroll
    for (int n = 0; n < 4; ++n) {
        int row = wc * 64 + n * 16 + r16;
        offB[n] = row * 32 + ((kq ^ ((row >> 1) & 3)) << 3);
    }

    f32x4 acc[4][4];
#pragma unroll
    for (int m = 0; m < 4; ++m)
#pragma unroll
        for (int n = 0; n < 4; ++n) acc[m][n] = (f32x4){0.f, 0.f, 0.f, 0.f};

    auto stage = [&](int h) {
        const int buf = h % 3;
        const int kt = ((h >> 1) << 6) + ((h & 1) << 5);
        u16* Abase = ldsbuf + buf * 12288;
        u16* Bbase = ldsbuf + buf * 12288 + 8192;
#pragma unroll
        for (int r = 0; r < 2; ++r) {
            int li = (r << 9) + t;
            int row = li >> 2;
            int kk = ((li & 3) ^ ((row >> 1) & 3)) << 3;
            GL_LDS16(A + (size_t)(m0 + row) * K + kt + kk,
                     Abase + ((li & ~63) << 3));
        }
        {
            int li = t;
            int row = li >> 2;
            int kk = ((li & 3) ^ ((row >> 1) & 3)) << 3;
            GL_LDS16(BT + (size_t)(n0 + row) * K + kt + kk,
                     Bbase + ((li & ~63) << 3));
        }
    };

    stage(0);
    stage(1);

    for (int p = 0; p < np; ++p) {
        if (p + 1 < np)
            asm volatile("s_waitcnt vmcnt(3)" ::: "memory");
        else
            asm volatile("s_waitcnt vmcnt(0)" ::: "memory");
        __builtin_amdgcn_sched_barrier(0);
        __builtin_amdgcn_s_barrier();
        __builtin_amdgcn_sched_barrier(0);

        const u16* base = ldsbuf + (p % 3) * 12288;
        short8 a[4], bfr[4];
#pragma unroll
        for (int mi = 0; mi < 4; ++mi)
            a[mi] = *(const short8*)(base + offA[mi]);
#pragma unroll
        for (int n = 0; n < 4; ++n)
            bfr[n] = *(const short8*)(base + 8192 + offB[n]);

        if (p + 2 < np) stage(p + 2);

        asm volatile("s_waitcnt lgkmcnt(0)" ::: "memory");
        __builtin_amdgcn_sched_barrier(0);
        __builtin_amdgcn_s_setprio(1);
#pragma unroll
        for (int mi = 0; mi < 4; ++mi)
#pragma unroll
            for (int n = 0; n < 4; ++n)
                acc[mi][n] = __builtin_amdgcn_mfma_f32_16x16x32_bf16(
                    a[mi], bfr[n], acc[mi][n], 0, 0, 0);
        __builtin_amdgcn_s_setprio(0);
        __builtin_amdgcn_sched_barrier(0);
    }

    if (FUSED) {
        const int seg = n0 >> 10;
        const float* bias = (seg == 0) ? b1 : (seg == 1) ? b2 : b3;
        u16* oh = (seg == 0) ? Qh : (seg == 1) ? Kh : Vb;
        u16* ol = (seg == 0) ? Ql : Kl;  // unused when seg==2
        const int nc0 = n0 & 1023;
        const int nplanes = (seg < 2) ? 2 : 1;
        u16* lds = ldsbuf;               // retired pipeline LDS: [256][128] u16
        for (int p = 0; p < nplanes; ++p) {
            __syncthreads();             // pipeline LDS free / prev plane done
#pragma unroll
            for (int n = 0; n < 4; ++n) {
                int col = wc * 64 + n * 16 + r16;
                float bvv = bias[nc0 + col];
#pragma unroll
                for (int mi = 0; mi < 4; ++mi) {
                    int row = wr * 64 + mi * 16 + kq * 4;
#pragma unroll
                    for (int j = 0; j < 4; ++j) {
                        float val = acc[mi][n][j] + bvv;
                        u16 hi = f2bf(val);
                        u16 w = p ? f2bf(val - bf2f(hi)) : hi;
                        lds[(row + j) * 128 + col] = w;
                    }
                }
            }
            __syncthreads();
            u16* dst = p ? ol : oh;
#pragma unroll
            for (int i = 0; i < 8; ++i) {
                int li = (i << 9) + t;          // 0..4095
                int row = li >> 4, ch = li & 15;
                short8 v = *(const short8*)&lds[row * 128 + ch * 8];
                *(short8*)(dst + (size_t)(m0 + row) * ldo + nc0 + ch * 8) = v;
            }
        }
    } else {
#pragma unroll
        for (int n = 0; n < 4; ++n) {
            int col = n0 + wc * 64 + n * 16 + r16;
            float bvv = b1[col];
#pragma unroll
            for (int mi = 0; mi < 4; ++mi) {
                int row = m0 + wr * 64 + mi * 16 + kq * 4;
#pragma unroll
                for (int j = 0; j < 4; ++j)
                    C[(size_t)(row + j) * ldo + col] = acc[mi][n][j] + bvv;
            }
        }
    }
}

// ---------------- MFMA diagonal-softmax + weighted = d*V --------------------
// 1024 blocks, 256 threads = 4 waves; (256,4): 4 blocks/CU = 1 round (R19).
__global__ __launch_bounds__(256, 4) void k_scores(
    const u16* __restrict__ Qhi, const u16* __restrict__ Qlo,
    const u16* __restrict__ Khi, const u16* __restrict__ Klo,
    const u16* __restrict__ Vb, const int* __restrict__ lengths,
    u16* __restrict__ Wt, int S, int D) {
    __shared__ __align__(16) u16 KsHi[2][4096];
    __shared__ __align__(16) u16 KsLo[2][4096];
    __shared__ float dbuf[128];

    const int wg = blockIdx.x;
    const int xcd = wg & 7, idc = wg >> 3;
    const int bh = (xcd << 4) + (idc >> 3);    // 16 (b,h) per XCD
    const int bx = idc & 7;
    const int b = bh >> 4, h = bh & 15;
    const int nchunk = S >> 6;                 // 16
    const int a0 = bx << 6;
    const int b0 = (nchunk - 1 - bx) << 6;

    const int t = threadIdx.x;
    const int lane = t & 63, wave = t >> 6;
    const int r16 = lane & 15, h2 = lane >> 4;
    const int len = lengths[b];

    short8 qh[2][2], ql[2][2];
#pragma unroll
    for (int m = 0; m < 2; ++m) {
        const int qm = m ? b0 : a0;
        const int row = qm + (wave << 4) + r16;
#pragma unroll
        for (int ks = 0; ks < 2; ++ks) {
            size_t off = ((size_t)(b * S) + row) * D + (h << 6) + (ks << 5) + (h2 << 3);
            qh[m][ks] = *(const short8*)(Qhi + off);
            ql[m][ks] = *(const short8*)(Qlo + off);
        }
    }

    float sum[2][4];
    float diag[2] = {-1e30f, -1e30f};
#pragma unroll
    for (int m = 0; m < 2; ++m)
#pragma unroll
        for (int r = 0; r < 4; ++r) sum[m][r] = 0.f;

    auto stage_k = [&](int j0, int bufi) {
#pragma unroll
        for (int p = 0; p < 2; ++p) {
            const int base_row = p * 32 + wave * 8;       // wave-uniform
            const int row = base_row + (lane >> 3);
            const int lc = (lane & 7) ^ (row & 7);
            size_t g = ((size_t)(b * S) + j0 + row) * D + (h << 6) + (lc << 3);
            GL_LDS16(Khi + g, &KsHi[bufi][base_row * 64]);
            GL_LDS16(Klo + g, &KsLo[bufi][base_row * 64]);
        }
    };

    const int jmax = min(b0 + 63, len - 1);
    stage_k(0, 0);
    for (int j0 = 0; j0 <= jmax; j0 += 64) {
        const int tb = (j0 >> 6) & 1;
        asm volatile("s_waitcnt vmcnt(0)" ::: "memory");
        __builtin_amdgcn_sched_barrier(0);
        __builtin_amdgcn_s_barrier();
        __builtin_amdgcn_sched_barrier(0);
        if (j0 + 64 <= jmax) stage_k(j0 + 64, tb ^ 1);

        f32x4 acc[2][4];
#pragma unroll
        for (int m = 0; m < 2; ++m)
#pragma unroll
            for (int n = 0; n < 4; ++n) acc[m][n] = (f32x4){0.f, 0.f, 0.f, 0.f};

#pragma unroll
        for (int ks = 0; ks < 2; ++ks) {
            short8 kh[4], kl[4];
#pragma unroll
            for (int n = 0; n < 4; ++n) {
                int row = (n << 4) + r16;
                int lc = (ks << 2) + h2;
                int phys = (row << 7) + ((lc ^ (row & 7)) << 4);
                kh[n] = *(const short8*)((const char*)&KsHi[tb][0] + phys);
                kl[n] = *(const short8*)((const char*)&KsLo[tb][0] + phys);
            }
#pragma unroll
            for (int m = 0; m < 2; ++m) {
                const int qm = m ? b0 : a0;
                if (j0 > qm) continue;
#pragma unroll
                for (int n = 0; n < 4; ++n) {
                    if (j0 + (n << 4) > qm + (wave << 4) + 15) continue;
                    acc[m][n] = __builtin_amdgcn_mfma_f32_16x16x32_bf16(qh[m][ks], kh[n], acc[m][n], 0, 0, 0);
                    acc[m][n] = __builtin_amdgcn_mfma_f32_16x16x32_bf16(qh[m][ks], kl[n], acc[m][n], 0, 0, 0);
                    acc[m][n] = __builtin_amdgcn_mfma_f32_16x16x32_bf16(ql[m][ks], kh[n], acc[m][n], 0, 0, 0);
                }
            }
        }

        const bool pad = (j0 + 64 > len);
#pragma unroll
        for (int m = 0; m < 2; ++m) {
            const int qm = m ? b0 : a0;
            if (j0 > qm) continue;
            const bool causal = (j0 == qm);
            if (causal || pad) {
#pragma unroll
                for (int n = 0; n < 4; ++n)
#pragma unroll
                    for (int r = 0; r < 4; ++r) {
                        int j = j0 + (n << 4) + r16;
                        int s = qm + (wave << 4) + (h2 << 2) + r;
                        if (j > s || j >= len) acc[m][n][r] = -1e30f;
                    }
                if (causal) {
#pragma unroll
                    for (int r = 0; r < 4; ++r)
                        if (r16 == (h2 << 2) + r) {
#pragma unroll
                            for (int n = 0; n < 4; ++n)
                                if (n == wave) diag[m] = acc[m][n][r];
                        }
                }
            }
#pragma unroll
            for (int r = 0; r < 4; ++r)
                sum[m][r] += __expf(acc[m][0][r]) + __expf(acc[m][1][r]) +
                             __expf(acc[m][2][r]) + __expf(acc[m][3][r]);
        }
    }

#pragma unroll
    for (int m = 0; m < 2; ++m)
#pragma unroll
        for (int r = 0; r < 4; ++r) {
            float sv = sum[m][r];
            sv += __shfl_xor(sv, 1);
            sv += __shfl_xor(sv, 2);
            sv += __shfl_xor(sv, 4);
            sv += __shfl_xor(sv, 8);
            sum[m][r] = sv;
        }

#pragma unroll
    for (int m = 0; m < 2; ++m)
#pragma unroll
        for (int r = 0; r < 4; ++r)
            if (r16 == (h2 << 2) + r)
                dbuf[(m << 6) + (wave << 4) + r16] = __expf(diag[m]) / sum[m][r];
    __syncthreads();

#pragma unroll
    for (int i = 0; i < 8; ++i) {
        int ri = i * 16 + (t >> 4);
        int c4 = (t & 15) << 2;
        int srow = (ri < 64) ? a0 + ri : b0 + ri - 64;
        float dv = dbuf[ri];
        const uint2 vv = *(const uint2*)(Vb + ((size_t)(b * S) + srow) * D + (h << 6) + c4);
        float x0 = bf2f((u16)(vv.x & 0xffffu)), x1 = bf2f((u16)(vv.x >> 16));
        float x2 = bf2f((u16)(vv.y & 0xffffu)), x3 = bf2f((u16)(vv.y >> 16));
        uint2 o;
        o.x = (unsigned)f2bf(x0 * dv) | ((unsigned)f2bf(x1 * dv) << 16);
        o.y = (unsigned)f2bf(x2 * dv) | ((unsigned)f2bf(x3 * dv) << 16);
        *(uint2*)(Wt + ((size_t)(b * S) + srow) * D + (h << 6) + c4) = o;
    }
}

extern "C" void kernel_launch(void* const* d_in, const int* in_sizes, int n_in,
                              void* d_out, int out_size, void* d_ws, size_t ws_size,
                              hipStream_t stream) {
    const float* batch = (const float*)d_in[0];
    const int* lengths = (const int*)d_in[1];
    const float* wq = (const float*)d_in[2];
    const float* bq = (const float*)d_in[3];
    const float* wk = (const float*)d_in[4];
    const float* bk = (const float*)d_in[5];
    const float* wv = (const float*)d_in[6];
    const float* bv = (const float*)d_in[7];
    const float* w0 = (const float*)d_in[8];
    const float* b0 = (const float*)d_in[9];

    const int D = in_sizes[3];            // 1024
    const int B = in_sizes[1];            // 8
    const int S = in_sizes[0] / (B * D);  // 1024
    const int H = 16;
    const int M = B * S;                  // 8192

    char* ws = (char*)d_ws;
    u16* Ab = (u16*)ws;    ws += (size_t)M * D * 2;
    u16* wcat = (u16*)ws;  ws += (size_t)3 * D * D * 2;   // [wqT; wkT; wvT]
    u16* w0T = (u16*)ws;   ws += (size_t)D * D * 2;
    u16* Qhi = (u16*)ws;   ws += (size_t)M * D * 2;
    u16* Qlo = (u16*)ws;   ws += (size_t)M * D * 2;
    u16* Khi = (u16*)ws;   ws += (size_t)M * D * 2;
    u16* Klo = (u16*)ws;   ws += (size_t)M * D * 2;
    u16* Vb = (u16*)ws;    ws += (size_t)M * D * 2;
    u16* Wtb = (u16*)ws;   ws += (size_t)M * D * 2;

    // 1. merged prep: convert (4096 blocks) + 4 transposes (1024 blocks)
    const int nconv = M * D / 8 / 256;    // 4096
    k_prep<<<nconv + 4 * (D / 64) * (D / 64), 256, 0, stream>>>(
        batch, Ab, nconv, wq, wk, wv, w0, wcat, w0T, D);

    // 2. fused QKV projection: (8192/256) x (3072/128) = 768 wgs
    k_gemm8<1><<<(M / 256) * (3 * D / 128), 512, 0, stream>>>(
        Ab, wcat, bq, bk, bv, Qhi, Qlo, Khi, Klo, Vb, nullptr, D, D);

    // 3. MFMA diagonal softmax + weighted = d*V (1024 blocks, 4/CU, 1 round)
    k_scores<<<(S / 128) * H * B, 256, 0, stream>>>(Qhi, Qlo, Khi, Klo, Vb,
                                                    lengths, Wtb, S, D);

    // 4. output projection -> d_out (f32): 256 wgs (BM=256 proven best)
    k_gemm8<0><<<(M / 256) * (D / 128), 512, 0, stream>>>(
        Wtb, w0T, b0, nullptr, nullptr, nullptr, nullptr, nullptr, nullptr, nullptr,
        (float*)d_out, D, D);
}

// Round 23
// 142.203 us; speedup vs baseline: 1.2310x; 1.0423x over previous
//
#include <hip/hip_runtime.h>
#include <hip/hip_bf16.h>
#include <stdint.h>
#include <math.h>

typedef short short8 __attribute__((ext_vector_type(8)));
typedef float f32x4 __attribute__((ext_vector_type(4)));
typedef unsigned short u16;

__device__ __forceinline__ u16 f2bf(float f) {
    unsigned u = __float_as_uint(f);
    unsigned r = 0x7FFFu + ((u >> 16) & 1u);
    return (u16)((u + r) >> 16);
}
__device__ __forceinline__ float bf2f(u16 h) {
    return __uint_as_float((unsigned)h << 16);
}

#define GL_LDS16(g, l)                                                         \
    __builtin_amdgcn_global_load_lds(                                          \
        (const __attribute__((address_space(1))) void*)(g),                    \
        (__attribute__((address_space(3))) void*)(l), 16, 0, 0)

// ------ merged prep: batch f32->bf16 convert + 4 weight transposes ----------
__global__ __launch_bounds__(256) void k_prep(
    const float* __restrict__ batch, u16* __restrict__ Ab, int nconv,
    const float* __restrict__ wq, const float* __restrict__ wk,
    const float* __restrict__ wv, const float* __restrict__ w0,
    u16* __restrict__ wcat, u16* __restrict__ w0T, int Dim) {
    __shared__ float tile[64][65];
    const int bid = blockIdx.x;
    const int t = threadIdx.x;
    if (bid < nconv) {
        int i = bid * 256 + t;
        const float4* s = (const float4*)batch + (size_t)i * 2;
        float4 a = s[0], b = s[1];
        uint4 o;
        o.x = (unsigned)f2bf(a.x) | ((unsigned)f2bf(a.y) << 16);
        o.y = (unsigned)f2bf(a.z) | ((unsigned)f2bf(a.w) << 16);
        o.z = (unsigned)f2bf(b.x) | ((unsigned)f2bf(b.y) << 16);
        o.w = (unsigned)f2bf(b.z) | ((unsigned)f2bf(b.w) << 16);
        ((uint4*)Ab)[i] = o;
        return;
    }
    const int id = bid - nconv;
    const int w = id >> 8, r = id & 255;
    const float* W = (w == 0) ? wq : (w == 1) ? wk : (w == 2) ? wv : w0;
    u16* WT = (w == 3) ? w0T : wcat + (size_t)w * Dim * Dim;
    const int k0 = (r & 15) * 64, n0 = (r >> 4) * 64;
    const int col = t & 63, rb = t >> 6;
#pragma unroll
    for (int i = 0; i < 16; ++i) {
        int rr = i * 4 + rb;
        tile[rr][col] = W[(size_t)(k0 + rr) * Dim + n0 + col];
    }
    __syncthreads();
#pragma unroll
    for (int i = 0; i < 16; ++i) {
        int rr = i * 4 + rb;
        WT[(size_t)(n0 + rr) * Dim + k0 + col] = f2bf(tile[col][rr]);
    }
}

// ---------------- phase-pipelined bf16 MFMA GEMM: BM=256, BN=128, BK=64 -----
// [R13/R19-proven optimum + R23 length-aware block skip: a block whose whole
//  row-range within its batch is >= lengths[b] skips the K-loop entirely.
//  FUSED=1: no writes (consumers guarded in k_scores); FUSED=0: epilogue
//  runs with zero acc -> writes bias broadcast (= reference for rows>=len).]
// LDS 72 KiB: 3-buffer HALF-TILE rotation, buf = phase % 3. Phase p:
// vmcnt(3) -> raw s_barrier -> 12 ds_read_b128 -> stage(p+2) (WAR-safe)
// -> lgkmcnt(0) -> 16 MFMA (setprio 1). vmcnt(0) only at last phase.
// 16B-slot XOR swizzle (slot ^= (row>>1)&3) on global source + LDS read.
template <int FUSED>
__global__ __launch_bounds__(512) void k_gemm8(
    const u16* __restrict__ A, const u16* __restrict__ BT,
    const float* __restrict__ b1, const float* __restrict__ b2,
    const float* __restrict__ b3,
    u16* __restrict__ Qh, u16* __restrict__ Ql,
    u16* __restrict__ Kh, u16* __restrict__ Kl,
    u16* __restrict__ Vb, float* __restrict__ C,
    const int* __restrict__ lengths, int S,
    int K, int ldo) {
    __shared__ __align__(16) u16 ldsbuf[36864];   // 72 KiB

    const int wg = blockIdx.x;
    const int xcd = wg & 7, idc = wg >> 3;          // grid % 8 == 0
    const int ml = idc & 3, nbn = idc >> 2;         // 4 m-tiles per XCD chunk
    const int m0 = ((xcd << 2) + ml) << 8;          // *256
    const int n0 = nbn << 7;                        // *128
    const int t = threadIdx.x;
    const int lane = t & 63, wave = t >> 6;
    const int wr = wave >> 1, wc = wave & 1;
    const int r16 = lane & 15, kq = lane >> 4;
    const int nt = K >> 6;                          // K-tiles (16)
    const int np = nt << 1;                         // phases (32)

    // length-aware skip: all rows of this block >= lengths[batch]?
    const int lenb = lengths[m0 / S];
    const bool skipblk = (m0 % S) >= lenb;

    int offA[4], offB[4];
#pragma unroll
    for (int mi = 0; mi < 4; ++mi) {
        int row = wr * 64 + mi * 16 + r16;
        offA[mi] = row * 32 + ((kq ^ ((row >> 1) & 3)) << 3);
    }
#pragma unroll
    for (int n = 0; n < 4; ++n) {
        int row = wc * 64 + n * 16 + r16;
        offB[n] = row * 32 + ((kq ^ ((row >> 1) & 3)) << 3);
    }

    f32x4 acc[4][4];
#pragma unroll
    for (int m = 0; m < 4; ++m)
#pragma unroll
        for (int n = 0; n < 4; ++n) acc[m][n] = (f32x4){0.f, 0.f, 0.f, 0.f};

    auto stage = [&](int h) {
        const int buf = h % 3;
        const int kt = ((h >> 1) << 6) + ((h & 1) << 5);
        u16* Abase = ldsbuf + buf * 12288;
        u16* Bbase = ldsbuf + buf * 12288 + 8192;
#pragma unroll
        for (int r = 0; r < 2; ++r) {
            int li = (r << 9) + t;
            int row = li >> 2;
            int kk = ((li & 3) ^ ((row >> 1) & 3)) << 3;
            GL_LDS16(A + (size_t)(m0 + row) * K + kt + kk,
                     Abase + ((li & ~63) << 3));
        }
        {
            int li = t;
            int row = li >> 2;
            int kk = ((li & 3) ^ ((row >> 1) & 3)) << 3;
            GL_LDS16(BT + (size_t)(n0 + row) * K + kt + kk,
                     Bbase + ((li & ~63) << 3));
        }
    };

    if (!skipblk) {
        stage(0);
        stage(1);

        for (int p = 0; p < np; ++p) {
            if (p + 1 < np)
                asm volatile("s_waitcnt vmcnt(3)" ::: "memory");
            else
                asm volatile("s_waitcnt vmcnt(0)" ::: "memory");
            __builtin_amdgcn_sched_barrier(0);
            __builtin_amdgcn_s_barrier();
            __builtin_amdgcn_sched_barrier(0);

            const u16* base = ldsbuf + (p % 3) * 12288;
            short8 a[4], bfr[4];
#pragma unroll
            for (int mi = 0; mi < 4; ++mi)
                a[mi] = *(const short8*)(base + offA[mi]);
#pragma unroll
            for (int n = 0; n < 4; ++n)
                bfr[n] = *(const short8*)(base + 8192 + offB[n]);

            if (p + 2 < np) stage(p + 2);

            asm volatile("s_waitcnt lgkmcnt(0)" ::: "memory");
            __builtin_amdgcn_sched_barrier(0);
            __builtin_amdgcn_s_setprio(1);
#pragma unroll
            for (int mi = 0; mi < 4; ++mi)
#pragma unroll
                for (int n = 0; n < 4; ++n)
                    acc[mi][n] = __builtin_amdgcn_mfma_f32_16x16x32_bf16(
                        a[mi], bfr[n], acc[mi][n], 0, 0, 0);
            __builtin_amdgcn_s_setprio(0);
            __builtin_amdgcn_sched_barrier(0);
        }
    }

    if (FUSED) {
        if (skipblk) return;   // outputs unused; consumers guarded in k_scores
        const int seg = n0 >> 10;
        const float* bias = (seg == 0) ? b1 : (seg == 1) ? b2 : b3;
        u16* oh = (seg == 0) ? Qh : (seg == 1) ? Kh : Vb;
        u16* ol = (seg == 0) ? Ql : Kl;  // unused when seg==2
        const int nc0 = n0 & 1023;
        const int nplanes = (seg < 2) ? 2 : 1;
        u16* lds = ldsbuf;               // retired pipeline LDS: [256][128] u16
        for (int p = 0; p < nplanes; ++p) {
            __syncthreads();             // pipeline LDS free / prev plane done
#pragma unroll
            for (int n = 0; n < 4; ++n) {
                int col = wc * 64 + n * 16 + r16;
                float bvv = bias[nc0 + col];
#pragma unroll
                for (int mi = 0; mi < 4; ++mi) {
                    int row = wr * 64 + mi * 16 + kq * 4;
#pragma unroll
                    for (int j = 0; j < 4; ++j) {
                        float val = acc[mi][n][j] + bvv;
                        u16 hi = f2bf(val);
                        u16 w = p ? f2bf(val - bf2f(hi)) : hi;
                        lds[(row + j) * 128 + col] = w;
                    }
                }
            }
            __syncthreads();
            u16* dst = p ? ol : oh;
#pragma unroll
            for (int i = 0; i < 8; ++i) {
                int li = (i << 9) + t;          // 0..4095
                int row = li >> 4, ch = li & 15;
                short8 v = *(const short8*)&lds[row * 128 + ch * 8];
                *(short8*)(dst + (size_t)(m0 + row) * ldo + nc0 + ch * 8) = v;
            }
        }
    } else {
        // skipped blocks fall through with acc=0 -> C = bias (reference value)
#pragma unroll
        for (int n = 0; n < 4; ++n) {
            int col = n0 + wc * 64 + n * 16 + r16;
            float bvv = b1[col];
#pragma unroll
            for (int mi = 0; mi < 4; ++mi) {
                int row = m0 + wr * 64 + mi * 16 + kq * 4;
#pragma unroll
                for (int j = 0; j < 4; ++j)
                    C[(size_t)(row + j) * ldo + col] = acc[mi][n][j] + bvv;
            }
        }
    }
}

// ---------------- MFMA diagonal-softmax + weighted = d*V --------------------
// 1024 blocks, 256 threads = 4 waves; (256,4): 4 blocks/CU = 1 round (R19).
// R23: NaN-guards for length-skipped producer blocks — d forced to 0 and
// weighted rows >= len written as exact 0 (kills garbage-Q/V propagation;
// also guarantees Wtb rows >= len are 0 for the out-GEMM).
__global__ __launch_bounds__(256, 4) void k_scores(
    const u16* __restrict__ Qhi, const u16* __restrict__ Qlo,
    const u16* __restrict__ Khi, const u16* __restrict__ Klo,
    const u16* __restrict__ Vb, const int* __restrict__ lengths,
    u16* __restrict__ Wt, int S, int D) {
    __shared__ __align__(16) u16 KsHi[2][4096];
    __shared__ __align__(16) u16 KsLo[2][4096];
    __shared__ float dbuf[128];

    const int wg = blockIdx.x;
    const int xcd = wg & 7, idc = wg >> 3;
    const int bh = (xcd << 4) + (idc >> 3);    // 16 (b,h) per XCD
    const int bx = idc & 7;
    const int b = bh >> 4, h = bh & 15;
    const int nchunk = S >> 6;                 // 16
    const int a0 = bx << 6;
    const int b0 = (nchunk - 1 - bx) << 6;

    const int t = threadIdx.x;
    const int lane = t & 63, wave = t >> 6;
    const int r16 = lane & 15, h2 = lane >> 4;
    const int len = lengths[b];

    short8 qh[2][2], ql[2][2];
#pragma unroll
    for (int m = 0; m < 2; ++m) {
        const int qm = m ? b0 : a0;
        const int row = qm + (wave << 4) + r16;
#pragma unroll
        for (int ks = 0; ks < 2; ++ks) {
            size_t off = ((size_t)(b * S) + row) * D + (h << 6) + (ks << 5) + (h2 << 3);
            qh[m][ks] = *(const short8*)(Qhi + off);
            ql[m][ks] = *(const short8*)(Qlo + off);
        }
    }

    float sum[2][4];
    float diag[2] = {-1e30f, -1e30f};
#pragma unroll
    for (int m = 0; m < 2; ++m)
#pragma unroll
        for (int r = 0; r < 4; ++r) sum[m][r] = 0.f;

    auto stage_k = [&](int j0, int bufi) {
#pragma unroll
        for (int p = 0; p < 2; ++p) {
            const int base_row = p * 32 + wave * 8;       // wave-uniform
            const int row = base_row + (lane >> 3);
            const int lc = (lane & 7) ^ (row & 7);
            size_t g = ((size_t)(b * S) + j0 + row) * D + (h << 6) + (lc << 3);
            GL_LDS16(Khi + g, &KsHi[bufi][base_row * 64]);
            GL_LDS16(Klo + g, &KsLo[bufi][base_row * 64]);
        }
    };

    const int jmax = min(b0 + 63, len - 1);
    stage_k(0, 0);
    for (int j0 = 0; j0 <= jmax; j0 += 64) {
        const int tb = (j0 >> 6) & 1;
        asm volatile("s_waitcnt vmcnt(0)" ::: "memory");
        __builtin_amdgcn_sched_barrier(0);
        __builtin_amdgcn_s_barrier();
        __builtin_amdgcn_sched_barrier(0);
        if (j0 + 64 <= jmax) stage_k(j0 + 64, tb ^ 1);

        f32x4 acc[2][4];
#pragma unroll
        for (int m = 0; m < 2; ++m)
#pragma unroll
            for (int n = 0; n < 4; ++n) acc[m][n] = (f32x4){0.f, 0.f, 0.f, 0.f};

#pragma unroll
        for (int ks = 0; ks < 2; ++ks) {
            short8 kh[4], kl[4];
#pragma unroll
            for (int n = 0; n < 4; ++n) {
                int row = (n << 4) + r16;
                int lc = (ks << 2) + h2;
                int phys = (row << 7) + ((lc ^ (row & 7)) << 4);
                kh[n] = *(const short8*)((const char*)&KsHi[tb][0] + phys);
                kl[n] = *(const short8*)((const char*)&KsLo[tb][0] + phys);
            }
#pragma unroll
            for (int m = 0; m < 2; ++m) {
                const int qm = m ? b0 : a0;
                if (j0 > qm) continue;
#pragma unroll
                for (int n = 0; n < 4; ++n) {
                    if (j0 + (n << 4) > qm + (wave << 4) + 15) continue;
                    acc[m][n] = __builtin_amdgcn_mfma_f32_16x16x32_bf16(qh[m][ks], kh[n], acc[m][n], 0, 0, 0);
                    acc[m][n] = __builtin_amdgcn_mfma_f32_16x16x32_bf16(qh[m][ks], kl[n], acc[m][n], 0, 0, 0);
                    acc[m][n] = __builtin_amdgcn_mfma_f32_16x16x32_bf16(ql[m][ks], kh[n], acc[m][n], 0, 0, 0);
                }
            }
        }

        const bool pad = (j0 + 64 > len);
#pragma unroll
        for (int m = 0; m < 2; ++m) {
            const int qm = m ? b0 : a0;
            if (j0 > qm) continue;
            const bool causal = (j0 == qm);
            if (causal || pad) {
#pragma unroll
                for (int n = 0; n < 4; ++n)
#pragma unroll
                    for (int r = 0; r < 4; ++r) {
                        int j = j0 + (n << 4) + r16;
                        int s = qm + (wave << 4) + (h2 << 2) + r;
                        if (j > s || j >= len) acc[m][n][r] = -1e30f;
                    }
                if (causal) {
#pragma unroll
                    for (int r = 0; r < 4; ++r)
                        if (r16 == (h2 << 2) + r) {
#pragma unroll
                            for (int n = 0; n < 4; ++n)
                                if (n == wave) diag[m] = acc[m][n][r];
                        }
                }
            }
#pragma unroll
            for (int r = 0; r < 4; ++r)
                sum[m][r] += __expf(acc[m][0][r]) + __expf(acc[m][1][r]) +
                             __expf(acc[m][2][r]) + __expf(acc[m][3][r]);
        }
    }

#pragma unroll
    for (int m = 0; m < 2; ++m)
#pragma unroll
        for (int r = 0; r < 4; ++r) {
            float sv = sum[m][r];
            sv += __shfl_xor(sv, 1);
            sv += __shfl_xor(sv, 2);
            sv += __shfl_xor(sv, 4);
            sv += __shfl_xor(sv, 8);
            sum[m][r] = sv;
        }

#pragma unroll
    for (int m = 0; m < 2; ++m)
#pragma unroll
        for (int r = 0; r < 4; ++r)
            if (r16 == (h2 << 2) + r) {
                int srow = (m ? b0 : a0) + (wave << 4) + r16;
                dbuf[(m << 6) + (wave << 4) + r16] =
                    (srow < len) ? __expf(diag[m]) / sum[m][r] : 0.f;
            }
    __syncthreads();

#pragma unroll
    for (int i = 0; i < 8; ++i) {
        int ri = i * 16 + (t >> 4);
        int c4 = (t & 15) << 2;
        int srow = (ri < 64) ? a0 + ri : b0 + ri - 64;
        uint2 o;
        if (srow < len) {
            float dv = dbuf[ri];
            const uint2 vv = *(const uint2*)(Vb + ((size_t)(b * S) + srow) * D + (h << 6) + c4);
            float x0 = bf2f((u16)(vv.x & 0xffffu)), x1 = bf2f((u16)(vv.x >> 16));
            float x2 = bf2f((u16)(vv.y & 0xffffu)), x3 = bf2f((u16)(vv.y >> 16));
            o.x = (unsigned)f2bf(x0 * dv) | ((unsigned)f2bf(x1 * dv) << 16);
            o.y = (unsigned)f2bf(x2 * dv) | ((unsigned)f2bf(x3 * dv) << 16);
        } else {
            o.x = 0u;   // exact zero: out-GEMM rows >= len must see Wtb = 0
            o.y = 0u;
        }
        *(uint2*)(Wt + ((size_t)(b * S) + srow) * D + (h << 6) + c4) = o;
    }
}

extern "C" void kernel_launch(void* const* d_in, const int* in_sizes, int n_in,
                              void* d_out, int out_size, void* d_ws, size_t ws_size,
                              hipStream_t stream) {
    const float* batch = (const float*)d_in[0];
    const int* lengths = (const int*)d_in[1];
    const float* wq = (const float*)d_in[2];
    const float* bq = (const float*)d_in[3];
    const float* wk = (const float*)d_in[4];
    const float* bk = (const float*)d_in[5];
    const float* wv = (const float*)d_in[6];
    const float* bv = (const float*)d_in[7];
    const float* w0 = (const float*)d_in[8];
    const float* b0 = (const float*)d_in[9];

    const int D = in_sizes[3];            // 1024
    const int B = in_sizes[1];            // 8
    const int S = in_sizes[0] / (B * D);  // 1024
    const int H = 16;
    const int M = B * S;                  // 8192

    char* ws = (char*)d_ws;
    u16* Ab = (u16*)ws;    ws += (size_t)M * D * 2;
    u16* wcat = (u16*)ws;  ws += (size_t)3 * D * D * 2;   // [wqT; wkT; wvT]
    u16* w0T = (u16*)ws;   ws += (size_t)D * D * 2;
    u16* Qhi = (u16*)ws;   ws += (size_t)M * D * 2;
    u16* Qlo = (u16*)ws;   ws += (size_t)M * D * 2;
    u16* Khi = (u16*)ws;   ws += (size_t)M * D * 2;
    u16* Klo = (u16*)ws;   ws += (size_t)M * D * 2;
    u16* Vb = (u16*)ws;    ws += (size_t)M * D * 2;
    u16* Wtb = (u16*)ws;   ws += (size_t)M * D * 2;

    // 1. merged prep: convert (4096 blocks) + 4 transposes (1024 blocks)
    const int nconv = M * D / 8 / 256;    // 4096
    k_prep<<<nconv + 4 * (D / 64) * (D / 64), 256, 0, stream>>>(
        batch, Ab, nconv, wq, wk, wv, w0, wcat, w0T, D);

    // 2. fused QKV projection: 768 wgs, length-skippable
    k_gemm8<1><<<(M / 256) * (3 * D / 128), 512, 0, stream>>>(
        Ab, wcat, bq, bk, bv, Qhi, Qlo, Khi, Klo, Vb, nullptr,
        lengths, S, D, D);

    // 3. MFMA diagonal softmax + weighted = d*V (1024 blocks, 4/CU, 1 round)
    k_scores<<<(S / 128) * H * B, 256, 0, stream>>>(Qhi, Qlo, Khi, Klo, Vb,
                                                    lengths, Wtb, S, D);

    // 4. output projection -> d_out (f32): 256 wgs, length-skippable (bias)
    k_gemm8<0><<<(M / 256) * (D / 128), 512, 0, stream>>>(
        Wtb, w0T, b0, nullptr, nullptr, nullptr, nullptr, nullptr, nullptr, nullptr,
        (float*)d_out, lengths, S, D, D);
}

// Round 24
// 138.877 us; speedup vs baseline: 1.2605x; 1.0240x over previous
//
#include <hip/hip_runtime.h>
#include <hip/hip_bf16.h>
#include <stdint.h>
#include <math.h>

typedef short short8 __attribute__((ext_vector_type(8)));
typedef float f32x4 __attribute__((ext_vector_type(4)));
typedef unsigned short u16;

__device__ __forceinline__ u16 f2bf(float f) {
    unsigned u = __float_as_uint(f);
    unsigned r = 0x7FFFu + ((u >> 16) & 1u);
    return (u16)((u + r) >> 16);
}
__device__ __forceinline__ float bf2f(u16 h) {
    return __uint_as_float((unsigned)h << 16);
}

#define GL_LDS16(g, l)                                                         \
    __builtin_amdgcn_global_load_lds(                                          \
        (const __attribute__((address_space(1))) void*)(g),                    \
        (__attribute__((address_space(3))) void*)(l), 16, 0, 0)

// ------ merged prep: batch f32->bf16 convert + 4 weight transposes ----------
__global__ __launch_bounds__(256) void k_prep(
    const float* __restrict__ batch, u16* __restrict__ Ab, int nconv,
    const float* __restrict__ wq, const float* __restrict__ wk,
    const float* __restrict__ wv, const float* __restrict__ w0,
    u16* __restrict__ wcat, u16* __restrict__ w0T, int Dim) {
    __shared__ float tile[64][65];
    const int bid = blockIdx.x;
    const int t = threadIdx.x;
    if (bid < nconv) {
        int i = bid * 256 + t;
        const float4* s = (const float4*)batch + (size_t)i * 2;
        float4 a = s[0], b = s[1];
        uint4 o;
        o.x = (unsigned)f2bf(a.x) | ((unsigned)f2bf(a.y) << 16);
        o.y = (unsigned)f2bf(a.z) | ((unsigned)f2bf(a.w) << 16);
        o.z = (unsigned)f2bf(b.x) | ((unsigned)f2bf(b.y) << 16);
        o.w = (unsigned)f2bf(b.z) | ((unsigned)f2bf(b.w) << 16);
        ((uint4*)Ab)[i] = o;
        return;
    }
    const int id = bid - nconv;
    const int w = id >> 8, r = id & 255;
    const float* W = (w == 0) ? wq : (w == 1) ? wk : (w == 2) ? wv : w0;
    u16* WT = (w == 3) ? w0T : wcat + (size_t)w * Dim * Dim;
    const int k0 = (r & 15) * 64, n0 = (r >> 4) * 64;
    const int col = t & 63, rb = t >> 6;
#pragma unroll
    for (int i = 0; i < 16; ++i) {
        int rr = i * 4 + rb;
        tile[rr][col] = W[(size_t)(k0 + rr) * Dim + n0 + col];
    }
    __syncthreads();
#pragma unroll
    for (int i = 0; i < 16; ++i) {
        int rr = i * 4 + rb;
        WT[(size_t)(n0 + rr) * Dim + k0 + col] = f2bf(tile[col][rr]);
    }
}

// ---------------- phase-pipelined bf16 MFMA GEMM: BM=256, BN=128, BK=64 -----
// [R13/R19 optimum + R23 length skip + R24 batch-interleaved m-tile remap:
//  mt = ml*8 + ((xcd+ml)&7) (bijective on [0,32)) -> every XCD owns one
//  m-tile of EACH row-block index {0,1,2,3} from 4 different batches, so
//  length-skippable work (rows >= lengths[b]) is uniform ~37.5% per XCD.
//  R23's mt = xcd*4+ml put each batch entirely on one XCD -> critical path
//  = longest batch, skip gain ~0. Skip: FUSED=1 writes nothing (consumers
//  guarded in k_scores); FUSED=0 writes bias broadcast (= reference).]
// LDS 72 KiB: 3-buffer HALF-TILE rotation, buf = phase % 3. Phase p:
// vmcnt(3) -> raw s_barrier -> 12 ds_read_b128 -> stage(p+2) (WAR-safe)
// -> lgkmcnt(0) -> 16 MFMA (setprio 1). vmcnt(0) only at last phase.
// 16B-slot XOR swizzle (slot ^= (row>>1)&3) on global source + LDS read.
template <int FUSED>
__global__ __launch_bounds__(512) void k_gemm8(
    const u16* __restrict__ A, const u16* __restrict__ BT,
    const float* __restrict__ b1, const float* __restrict__ b2,
    const float* __restrict__ b3,
    u16* __restrict__ Qh, u16* __restrict__ Ql,
    u16* __restrict__ Kh, u16* __restrict__ Kl,
    u16* __restrict__ Vb, float* __restrict__ C,
    const int* __restrict__ lengths, int S,
    int K, int ldo) {
    __shared__ __align__(16) u16 ldsbuf[36864];   // 72 KiB

    const int wg = blockIdx.x;
    const int xcd = wg & 7, idc = wg >> 3;          // grid % 8 == 0
    const int ml = idc & 3, nbn = idc >> 2;
    const int mt = ml * 8 + ((xcd + ml) & 7);       // batch-interleaved m-tile
    const int m0 = mt << 8;                         // *256
    const int n0 = nbn << 7;                        // *128
    const int t = threadIdx.x;
    const int lane = t & 63, wave = t >> 6;
    const int wr = wave >> 1, wc = wave & 1;
    const int r16 = lane & 15, kq = lane >> 4;
    const int nt = K >> 6;                          // K-tiles (16)
    const int np = nt << 1;                         // phases (32)

    // length-aware skip: all rows of this block >= lengths[batch]?
    const int lenb = lengths[m0 / S];
    const bool skipblk = (m0 % S) >= lenb;

    int offA[4], offB[4];
#pragma unroll
    for (int mi = 0; mi < 4; ++mi) {
        int row = wr * 64 + mi * 16 + r16;
        offA[mi] = row * 32 + ((kq ^ ((row >> 1) & 3)) << 3);
    }
#pragma unroll
    for (int n = 0; n < 4; ++n) {
        int row = wc * 64 + n * 16 + r16;
        offB[n] = row * 32 + ((kq ^ ((row >> 1) & 3)) << 3);
    }

    f32x4 acc[4][4];
#pragma unroll
    for (int m = 0; m < 4; ++m)
#pragma unroll
        for (int n = 0; n < 4; ++n) acc[m][n] = (f32x4){0.f, 0.f, 0.f, 0.f};

    auto stage = [&](int h) {
        const int buf = h % 3;
        const int kt = ((h >> 1) << 6) + ((h & 1) << 5);
        u16* Abase = ldsbuf + buf * 12288;
        u16* Bbase = ldsbuf + buf * 12288 + 8192;
#pragma unroll
        for (int r = 0; r < 2; ++r) {
            int li = (r << 9) + t;
            int row = li >> 2;
            int kk = ((li & 3) ^ ((row >> 1) & 3)) << 3;
            GL_LDS16(A + (size_t)(m0 + row) * K + kt + kk,
                     Abase + ((li & ~63) << 3));
        }
        {
            int li = t;
            int row = li >> 2;
            int kk = ((li & 3) ^ ((row >> 1) & 3)) << 3;
            GL_LDS16(BT + (size_t)(n0 + row) * K + kt + kk,
                     Bbase + ((li & ~63) << 3));
        }
    };

    if (!skipblk) {
        stage(0);
        stage(1);

        for (int p = 0; p < np; ++p) {
            if (p + 1 < np)
                asm volatile("s_waitcnt vmcnt(3)" ::: "memory");
            else
                asm volatile("s_waitcnt vmcnt(0)" ::: "memory");
            __builtin_amdgcn_sched_barrier(0);
            __builtin_amdgcn_s_barrier();
            __builtin_amdgcn_sched_barrier(0);

            const u16* base = ldsbuf + (p % 3) * 12288;
            short8 a[4], bfr[4];
#pragma unroll
            for (int mi = 0; mi < 4; ++mi)
                a[mi] = *(const short8*)(base + offA[mi]);
#pragma unroll
            for (int n = 0; n < 4; ++n)
                bfr[n] = *(const short8*)(base + 8192 + offB[n]);

            if (p + 2 < np) stage(p + 2);

            asm volatile("s_waitcnt lgkmcnt(0)" ::: "memory");
            __builtin_amdgcn_sched_barrier(0);
            __builtin_amdgcn_s_setprio(1);
#pragma unroll
            for (int mi = 0; mi < 4; ++mi)
#pragma unroll
                for (int n = 0; n < 4; ++n)
                    acc[mi][n] = __builtin_amdgcn_mfma_f32_16x16x32_bf16(
                        a[mi], bfr[n], acc[mi][n], 0, 0, 0);
            __builtin_amdgcn_s_setprio(0);
            __builtin_amdgcn_sched_barrier(0);
        }
    }

    if (FUSED) {
        if (skipblk) return;   // outputs unused; consumers guarded in k_scores
        const int seg = n0 >> 10;
        const float* bias = (seg == 0) ? b1 : (seg == 1) ? b2 : b3;
        u16* oh = (seg == 0) ? Qh : (seg == 1) ? Kh : Vb;
        u16* ol = (seg == 0) ? Ql : Kl;  // unused when seg==2
        const int nc0 = n0 & 1023;
        const int nplanes = (seg < 2) ? 2 : 1;
        u16* lds = ldsbuf;               // retired pipeline LDS: [256][128] u16
        for (int p = 0; p < nplanes; ++p) {
            __syncthreads();             // pipeline LDS free / prev plane done
#pragma unroll
            for (int n = 0; n < 4; ++n) {
                int col = wc * 64 + n * 16 + r16;
                float bvv = bias[nc0 + col];
#pragma unroll
                for (int mi = 0; mi < 4; ++mi) {
                    int row = wr * 64 + mi * 16 + kq * 4;
#pragma unroll
                    for (int j = 0; j < 4; ++j) {
                        float val = acc[mi][n][j] + bvv;
                        u16 hi = f2bf(val);
                        u16 w = p ? f2bf(val - bf2f(hi)) : hi;
                        lds[(row + j) * 128 + col] = w;
                    }
                }
            }
            __syncthreads();
            u16* dst = p ? ol : oh;
#pragma unroll
            for (int i = 0; i < 8; ++i) {
                int li = (i << 9) + t;          // 0..4095
                int row = li >> 4, ch = li & 15;
                short8 v = *(const short8*)&lds[row * 128 + ch * 8];
                *(short8*)(dst + (size_t)(m0 + row) * ldo + nc0 + ch * 8) = v;
            }
        }
    } else {
        // skipped blocks fall through with acc=0 -> C = bias (reference value)
#pragma unroll
        for (int n = 0; n < 4; ++n) {
            int col = n0 + wc * 64 + n * 16 + r16;
            float bvv = b1[col];
#pragma unroll
            for (int mi = 0; mi < 4; ++mi) {
                int row = m0 + wr * 64 + mi * 16 + kq * 4;
#pragma unroll
                for (int j = 0; j < 4; ++j)
                    C[(size_t)(row + j) * ldo + col] = acc[mi][n][j] + bvv;
            }
        }
    }
}

// ---------------- MFMA diagonal-softmax + weighted = d*V --------------------
// 1024 blocks, 256 threads = 4 waves; (256,4): 4 blocks/CU = 1 round.
// R24: batch-interleaved (b,h) remap — h = idc>>3, b = (xcd+h)&7 (bijective)
// so per-XCD work ~ mean(len), not len[xcd] (R23 put batch b on XCD b).
// R23 NaN-guards kept: d=0 and weighted=0 for rows >= len.
__global__ __launch_bounds__(256, 4) void k_scores(
    const u16* __restrict__ Qhi, const u16* __restrict__ Qlo,
    const u16* __restrict__ Khi, const u16* __restrict__ Klo,
    const u16* __restrict__ Vb, const int* __restrict__ lengths,
    u16* __restrict__ Wt, int S, int D) {
    __shared__ __align__(16) u16 KsHi[2][4096];
    __shared__ __align__(16) u16 KsLo[2][4096];
    __shared__ float dbuf[128];

    const int wg = blockIdx.x;
    const int xcd = wg & 7, idc = wg >> 3;
    const int h = idc >> 3;                    // 0..15
    const int b = (xcd + h) & 7;               // batch-interleaved
    const int bx = idc & 7;
    const int nchunk = S >> 6;                 // 16
    const int a0 = bx << 6;
    const int b0 = (nchunk - 1 - bx) << 6;

    const int t = threadIdx.x;
    const int lane = t & 63, wave = t >> 6;
    const int r16 = lane & 15, h2 = lane >> 4;
    const int len = lengths[b];

    short8 qh[2][2], ql[2][2];
#pragma unroll
    for (int m = 0; m < 2; ++m) {
        const int qm = m ? b0 : a0;
        const int row = qm + (wave << 4) + r16;
#pragma unroll
        for (int ks = 0; ks < 2; ++ks) {
            size_t off = ((size_t)(b * S) + row) * D + (h << 6) + (ks << 5) + (h2 << 3);
            qh[m][ks] = *(const short8*)(Qhi + off);
            ql[m][ks] = *(const short8*)(Qlo + off);
        }
    }

    float sum[2][4];
    float diag[2] = {-1e30f, -1e30f};
#pragma unroll
    for (int m = 0; m < 2; ++m)
#pragma unroll
        for (int r = 0; r < 4; ++r) sum[m][r] = 0.f;

    auto stage_k = [&](int j0, int bufi) {
#pragma unroll
        for (int p = 0; p < 2; ++p) {
            const int base_row = p * 32 + wave * 8;       // wave-uniform
            const int row = base_row + (lane >> 3);
            const int lc = (lane & 7) ^ (row & 7);
            size_t g = ((size_t)(b * S) + j0 + row) * D + (h << 6) + (lc << 3);
            GL_LDS16(Khi + g, &KsHi[bufi][base_row * 64]);
            GL_LDS16(Klo + g, &KsLo[bufi][base_row * 64]);
        }
    };

    const int jmax = min(b0 + 63, len - 1);
    stage_k(0, 0);
    for (int j0 = 0; j0 <= jmax; j0 += 64) {
        const int tb = (j0 >> 6) & 1;
        asm volatile("s_waitcnt vmcnt(0)" ::: "memory");
        __builtin_amdgcn_sched_barrier(0);
        __builtin_amdgcn_s_barrier();
        __builtin_amdgcn_sched_barrier(0);
        if (j0 + 64 <= jmax) stage_k(j0 + 64, tb ^ 1);

        f32x4 acc[2][4];
#pragma unroll
        for (int m = 0; m < 2; ++m)
#pragma unroll
            for (int n = 0; n < 4; ++n) acc[m][n] = (f32x4){0.f, 0.f, 0.f, 0.f};

#pragma unroll
        for (int ks = 0; ks < 2; ++ks) {
            short8 kh[4], kl[4];
#pragma unroll
            for (int n = 0; n < 4; ++n) {
                int row = (n << 4) + r16;
                int lc = (ks << 2) + h2;
                int phys = (row << 7) + ((lc ^ (row & 7)) << 4);
                kh[n] = *(const short8*)((const char*)&KsHi[tb][0] + phys);
                kl[n] = *(const short8*)((const char*)&KsLo[tb][0] + phys);
            }
#pragma unroll
            for (int m = 0; m < 2; ++m) {
                const int qm = m ? b0 : a0;
                if (j0 > qm) continue;
#pragma unroll
                for (int n = 0; n < 4; ++n) {
                    if (j0 + (n << 4) > qm + (wave << 4) + 15) continue;
                    acc[m][n] = __builtin_amdgcn_mfma_f32_16x16x32_bf16(qh[m][ks], kh[n], acc[m][n], 0, 0, 0);
                    acc[m][n] = __builtin_amdgcn_mfma_f32_16x16x32_bf16(qh[m][ks], kl[n], acc[m][n], 0, 0, 0);
                    acc[m][n] = __builtin_amdgcn_mfma_f32_16x16x32_bf16(ql[m][ks], kh[n], acc[m][n], 0, 0, 0);
                }
            }
        }

        const bool pad = (j0 + 64 > len);
#pragma unroll
        for (int m = 0; m < 2; ++m) {
            const int qm = m ? b0 : a0;
            if (j0 > qm) continue;
            const bool causal = (j0 == qm);
            if (causal || pad) {
#pragma unroll
                for (int n = 0; n < 4; ++n)
#pragma unroll
                    for (int r = 0; r < 4; ++r) {
                        int j = j0 + (n << 4) + r16;
                        int s = qm + (wave << 4) + (h2 << 2) + r;
                        if (j > s || j >= len) acc[m][n][r] = -1e30f;
                    }
                if (causal) {
#pragma unroll
                    for (int r = 0; r < 4; ++r)
                        if (r16 == (h2 << 2) + r) {
#pragma unroll
                            for (int n = 0; n < 4; ++n)
                                if (n == wave) diag[m] = acc[m][n][r];
                        }
                }
            }
#pragma unroll
            for (int r = 0; r < 4; ++r)
                sum[m][r] += __expf(acc[m][0][r]) + __expf(acc[m][1][r]) +
                             __expf(acc[m][2][r]) + __expf(acc[m][3][r]);
        }
    }

#pragma unroll
    for (int m = 0; m < 2; ++m)
#pragma unroll
        for (int r = 0; r < 4; ++r) {
            float sv = sum[m][r];
            sv += __shfl_xor(sv, 1);
            sv += __shfl_xor(sv, 2);
            sv += __shfl_xor(sv, 4);
            sv += __shfl_xor(sv, 8);
            sum[m][r] = sv;
        }

#pragma unroll
    for (int m = 0; m < 2; ++m)
#pragma unroll
        for (int r = 0; r < 4; ++r)
            if (r16 == (h2 << 2) + r) {
                int srow = (m ? b0 : a0) + (wave << 4) + r16;
                dbuf[(m << 6) + (wave << 4) + r16] =
                    (srow < len) ? __expf(diag[m]) / sum[m][r] : 0.f;
            }
    __syncthreads();

#pragma unroll
    for (int i = 0; i < 8; ++i) {
        int ri = i * 16 + (t >> 4);
        int c4 = (t & 15) << 2;
        int srow = (ri < 64) ? a0 + ri : b0 + ri - 64;
        uint2 o;
        if (srow < len) {
            float dv = dbuf[ri];
            const uint2 vv = *(const uint2*)(Vb + ((size_t)(b * S) + srow) * D + (h << 6) + c4);
            float x0 = bf2f((u16)(vv.x & 0xffffu)), x1 = bf2f((u16)(vv.x >> 16));
            float x2 = bf2f((u16)(vv.y & 0xffffu)), x3 = bf2f((u16)(vv.y >> 16));
            o.x = (unsigned)f2bf(x0 * dv) | ((unsigned)f2bf(x1 * dv) << 16);
            o.y = (unsigned)f2bf(x2 * dv) | ((unsigned)f2bf(x3 * dv) << 16);
        } else {
            o.x = 0u;   // exact zero: out-GEMM rows >= len must see Wtb = 0
            o.y = 0u;
        }
        *(uint2*)(Wt + ((size_t)(b * S) + srow) * D + (h << 6) + c4) = o;
    }
}

extern "C" void kernel_launch(void* const* d_in, const int* in_sizes, int n_in,
                              void* d_out, int out_size, void* d_ws, size_t ws_size,
                              hipStream_t stream) {
    const float* batch = (const float*)d_in[0];
    const int* lengths = (const int*)d_in[1];
    const float* wq = (const float*)d_in[2];
    const float* bq = (const float*)d_in[3];
    const float* wk = (const float*)d_in[4];
    const float* bk = (const float*)d_in[5];
    const float* wv = (const float*)d_in[6];
    const float* bv = (const float*)d_in[7];
    const float* w0 = (const float*)d_in[8];
    const float* b0 = (const float*)d_in[9];

    const int D = in_sizes[3];            // 1024
    const int B = in_sizes[1];            // 8
    const int S = in_sizes[0] / (B * D);  // 1024
    const int H = 16;
    const int M = B * S;                  // 8192

    char* ws = (char*)d_ws;
    u16* Ab = (u16*)ws;    ws += (size_t)M * D * 2;
    u16* wcat = (u16*)ws;  ws += (size_t)3 * D * D * 2;   // [wqT; wkT; wvT]
    u16* w0T = (u16*)ws;   ws += (size_t)D * D * 2;
    u16* Qhi = (u16*)ws;   ws += (size_t)M * D * 2;
    u16* Qlo = (u16*)ws;   ws += (size_t)M * D * 2;
    u16* Khi = (u16*)ws;   ws += (size_t)M * D * 2;
    u16* Klo = (u16*)ws;   ws += (size_t)M * D * 2;
    u16* Vb = (u16*)ws;    ws += (size_t)M * D * 2;
    u16* Wtb = (u16*)ws;   ws += (size_t)M * D * 2;

    // 1. merged prep: convert (4096 blocks) + 4 transposes (1024 blocks)
    const int nconv = M * D / 8 / 256;    // 4096
    k_prep<<<nconv + 4 * (D / 64) * (D / 64), 256, 0, stream>>>(
        batch, Ab, nconv, wq, wk, wv, w0, wcat, w0T, D);

    // 2. fused QKV projection: 768 wgs, length-skippable, batch-interleaved
    k_gemm8<1><<<(M / 256) * (3 * D / 128), 512, 0, stream>>>(
        Ab, wcat, bq, bk, bv, Qhi, Qlo, Khi, Klo, Vb, nullptr,
        lengths, S, D, D);

    // 3. MFMA diagonal softmax + weighted = d*V (batch-interleaved)
    k_scores<<<(S / 128) * H * B, 256, 0, stream>>>(Qhi, Qlo, Khi, Klo, Vb,
                                                    lengths, Wtb, S, D);

    // 4. output projection -> d_out (f32): 256 wgs, length-skippable
    k_gemm8<0><<<(M / 256) * (D / 128), 512, 0, stream>>>(
        Wtb, w0T, b0, nullptr, nullptr, nullptr, nullptr, nullptr, nullptr, nullptr,
        (float*)d_out, lengths, S, D, D);
}